// Round 1
// baseline (3503.615 us; speedup 1.0000x reference)
//
#include <hip/hip_runtime.h>
#include <math.h>

// Problem constants (from reference)
constexpr int NN    = 50000;
constexpr int NE    = 400000;
constexpr int HID   = 128;
constexpr int MLPIN = 432;   // 3*128 + 32 + 16

// Workspace layout (float offsets)
//  vecp : [N,3,384]  (vec1|vec2|vec3 along last dim)   57,600,000
//  vdot : [N,128]                                        6,400,000
//  hagg : [N,128]                                        6,400,000
//  obuf : [N,384]                                       19,200,000
constexpr size_t OFF_VECP = 0;
constexpr size_t OFF_VDOT = 57600000;
constexpr size_t OFF_HAGG = 64000000;
constexpr size_t OFF_OBUF = 70400000;
constexpr size_t WS_FLOATS = 89600000;

// ---------------------------------------------------------------------------
// Tiled fp32 GEMM: C[M,384] = A[M,128] @ B[128,384] (+ bias). 128x128 tiles,
// 256 threads, 8x8 micro-tile per thread, K staged in 16-chunks via LDS.
// ---------------------------------------------------------------------------
template<bool BIAS>
__global__ void __launch_bounds__(256, 2)
gemm128(const float* __restrict__ A, const float* __restrict__ B,
        const float* __restrict__ bias, float* __restrict__ C, int M)
{
    __shared__ __align__(16) float As[16 * 132];  // [k][m], padded
    __shared__ __align__(16) float Bs[16 * 132];  // [k][n], padded
    const int tid = threadIdx.x;
    const int m0 = blockIdx.y * 128;
    const int n0 = blockIdx.x * 128;
    const int ty = tid >> 4, tx = tid & 15;

    float acc[64];
#pragma unroll
    for (int i = 0; i < 64; ++i) acc[i] = 0.f;

    for (int kc = 0; kc < 128; kc += 16) {
        // A tile (transposed into LDS)
#pragma unroll
        for (int p = 0; p < 2; ++p) {
            int m  = (tid >> 2) + p * 64;
            int kq = (tid & 3) * 4;
            int mm = (m0 + m < M) ? (m0 + m) : 0;  // clamp (row 0 always valid)
            float4 v = *(const float4*)&A[(size_t)mm * 128 + kc + kq];
            As[(kq + 0) * 132 + m] = v.x; As[(kq + 1) * 132 + m] = v.y;
            As[(kq + 2) * 132 + m] = v.z; As[(kq + 3) * 132 + m] = v.w;
        }
        // B tile
#pragma unroll
        for (int p = 0; p < 2; ++p) {
            int t = tid + p * 256;
            int k = t >> 5, c4 = (t & 31) * 4;
            *(float4*)&Bs[k * 132 + c4] =
                *(const float4*)&B[(size_t)(kc + k) * 384 + n0 + c4];
        }
        __syncthreads();
#pragma unroll
        for (int kk = 0; kk < 16; ++kk) {
            float a[8], b[8];
            *(float4*)&a[0] = *(const float4*)&As[kk * 132 + ty * 8];
            *(float4*)&a[4] = *(const float4*)&As[kk * 132 + ty * 8 + 4];
            *(float4*)&b[0] = *(const float4*)&Bs[kk * 132 + tx * 8];
            *(float4*)&b[4] = *(const float4*)&Bs[kk * 132 + tx * 8 + 4];
#pragma unroll
            for (int i = 0; i < 8; ++i)
#pragma unroll
                for (int j = 0; j < 8; ++j) acc[i * 8 + j] += a[i] * b[j];
        }
        __syncthreads();
    }
#pragma unroll
    for (int i = 0; i < 8; ++i) {
        int m = m0 + ty * 8 + i;
        if (m < M) {
            float o0[4], o1[4];
#pragma unroll
            for (int j = 0; j < 4; ++j) {
                float v0 = acc[i * 8 + j], v1 = acc[i * 8 + 4 + j];
                if (BIAS) {
                    v0 += bias[n0 + tx * 8 + j];
                    v1 += bias[n0 + tx * 8 + 4 + j];
                }
                o0[j] = v0; o1[j] = v1;
            }
            float* dst = &C[(size_t)m * 384 + n0 + tx * 8];
            *(float4*)dst       = *(float4*)o0;
            *(float4*)(dst + 4) = *(float4*)o1;
        }
    }
}

// ---------------------------------------------------------------------------
// prep: vec_dot = sum_v vec1*vec2 ; zero h_aggr and the dvec region of d_out
// (d_ws/d_out are re-poisoned 0xAA before every timed launch)
// ---------------------------------------------------------------------------
__global__ void prep_kernel(const float* __restrict__ vecp, float* __restrict__ vdot,
                            float* __restrict__ hagg, float* __restrict__ dvec)
{
    int idx = blockIdx.x * 256 + threadIdx.x;   // exactly N*128 threads
    int n = idx >> 7, k = idx & 127;
    size_t b = (size_t)n * 1152;
    float s = vecp[b + k]       * vecp[b + 128 + k]
            + vecp[b + 384 + k] * vecp[b + 512 + k]
            + vecp[b + 768 + k] * vecp[b + 896 + k];
    vdot[idx] = s;
    hagg[idx] = 0.f;
    size_t db = (size_t)n * 384 + k;
    dvec[db] = 0.f; dvec[db + 128] = 0.f; dvec[db + 256] = 0.f;
}

// ---------------------------------------------------------------------------
// finalize: o = obuf (h_aggr@Wop+bop already computed); dh = vdot*o2 + o3;
// dvec (holds vec_aggr) += vec3 * o1
// ---------------------------------------------------------------------------
__global__ void fin_kernel(const float* __restrict__ vecp, const float* __restrict__ vdot,
                           const float* __restrict__ obuf, float* __restrict__ dh,
                           float* __restrict__ dvec)
{
    int idx = blockIdx.x * 256 + threadIdx.x;
    int n = idx >> 7, k = idx & 127;
    const float* o = obuf + (size_t)n * 384;
    float o1 = o[k], o2 = o[128 + k], o3 = o[256 + k];
    dh[idx] = vdot[idx] * o2 + o3;
    size_t vb = (size_t)n * 1152 + 256 + k;  // vec3
    size_t db = (size_t)n * 384 + k;
    dvec[db]       += vecp[vb]       * o1;
    dvec[db + 128] += vecp[vb + 384] * o1;
    dvec[db + 256] += vecp[vb + 768] * o1;
}

// ---------------------------------------------------------------------------
// Fused edge kernel: 32 edges/block, 256 threads.
// mlp_in built segment-wise into segT [j][e] (transposed); W1/W2/W3 streamed
// through a 32x128 LDS chunk; 4x4 register micro-tiles (eg=tid&7, kg=tid>>3).
// LDS ~48.8KB -> 3 blocks/CU.
// ---------------------------------------------------------------------------
#define FMA16(acc, a, b) do { \
  acc[0]+=a.x*b.x;  acc[1]+=a.x*b.y;  acc[2]+=a.x*b.z;  acc[3]+=a.x*b.w;  \
  acc[4]+=a.y*b.x;  acc[5]+=a.y*b.y;  acc[6]+=a.y*b.z;  acc[7]+=a.y*b.w;  \
  acc[8]+=a.z*b.x;  acc[9]+=a.z*b.y;  acc[10]+=a.z*b.z; acc[11]+=a.z*b.w; \
  acc[12]+=a.w*b.x; acc[13]+=a.w*b.y; acc[14]+=a.w*b.z; acc[15]+=a.w*b.w; } while(0)

__global__ void __launch_bounds__(256, 3)
edge_kernel(const float* __restrict__ h, const float* __restrict__ vecp,
            const float* __restrict__ coord, const int* __restrict__ eidx,
            const float* __restrict__ eattr,
            const float* __restrict__ W1, const float* __restrict__ b1,
            const float* __restrict__ W2, const float* __restrict__ b2,
            const float* __restrict__ W3, const float* __restrict__ b3,
            float* __restrict__ hagg, float* __restrict__ dvec)
{
    __shared__ __align__(16) float segT[128 * 32];  // A operand, [j][e]; reused as x2T
    __shared__ __align__(16) float wc[32 * 128];    // weight chunk [j][k]
    __shared__ __align__(16) float x1T[128 * 32];
    __shared__ int   s_row[32], s_col[32];
    __shared__ float s_xij[32 * 3];
    __shared__ float s_d[32];

    const int tid = threadIdx.x;
    const int e0 = (tid & 7) * 4;     // 8 e-groups x 4
    const int k0 = (tid >> 3) * 4;    // 32 k-groups x 4
    const int eb = blockIdx.x * 32;   // E = 12500 * 32 exactly

    if (tid < 32) {
        int r = eidx[eb + tid], c = eidx[NE + eb + tid];
        s_row[tid] = r; s_col[tid] = c;
        float x0 = coord[r * 3 + 0] - coord[c * 3 + 0];
        float x1 = coord[r * 3 + 1] - coord[c * 3 + 1];
        float x2 = coord[r * 3 + 2] - coord[c * 3 + 2];
        s_xij[tid * 3 + 0] = x0; s_xij[tid * 3 + 1] = x1; s_xij[tid * 3 + 2] = x2;
        s_d[tid] = sqrtf(x0 * x0 + x1 * x1 + x2 * x2 + 1e-8f);
    }
    __syncthreads();

    float acc[16];
#pragma unroll
    for (int i = 0; i < 16; ++i) acc[i] = 0.f;

    // mlp_in segments: [h[row](128) | h[col](128) | rbf(32) | cross(128) | eattr(16->pad32)]
    const int seg_off[5] = {0, 128, 256, 288, 416};
    const int seg_len[5] = {128, 128, 32, 128, 32};

    for (int seg = 0; seg < 5; ++seg) {
        // ---- build segT for this segment ----
        if (seg < 2) {
            const int e = tid >> 3, q = tid & 7, j0 = q * 16;
            const int node = (seg == 0) ? s_row[e] : s_col[e];
            const float* src = h + (size_t)node * 128 + j0;
#pragma unroll
            for (int f = 0; f < 4; ++f) {
                float4 v = *(const float4*)(src + f * 4);
                segT[(j0 + f * 4 + 0) * 32 + e] = v.x;
                segT[(j0 + f * 4 + 1) * 32 + e] = v.y;
                segT[(j0 + f * 4 + 2) * 32 + e] = v.z;
                segT[(j0 + f * 4 + 3) * 32 + e] = v.w;
            }
        } else if (seg == 2) {
            const float delta = 5.0f / 31.0f;
            const float coeff = -0.5f / (delta * delta);
            for (int t = tid; t < 1024; t += 256) {
                int e = t & 31, j = t >> 5;
                float dd = s_d[e] - (float)j * delta;
                segT[j * 32 + e] = expf(coeff * dd * dd);
            }
        } else if (seg == 3) {
            // cross[e][k] = sum_v vec1[row,v,k] * vec2[col,v,k]
            const int e = tid >> 3, q = tid & 7, kk0 = q * 16;
            const float* vr = vecp + (size_t)s_row[e] * 1152 + kk0;        // vec1
            const float* vc = vecp + (size_t)s_col[e] * 1152 + 128 + kk0;  // vec2
            float cr[16];
#pragma unroll
            for (int f = 0; f < 16; ++f) cr[f] = 0.f;
#pragma unroll
            for (int v = 0; v < 3; ++v) {
#pragma unroll
                for (int f = 0; f < 4; ++f) {
                    float4 av = *(const float4*)(vr + v * 384 + f * 4);
                    float4 bv = *(const float4*)(vc + v * 384 + f * 4);
                    cr[f * 4 + 0] += av.x * bv.x; cr[f * 4 + 1] += av.y * bv.y;
                    cr[f * 4 + 2] += av.z * bv.z; cr[f * 4 + 3] += av.w * bv.w;
                }
            }
#pragma unroll
            for (int f = 0; f < 16; ++f) segT[(kk0 + f) * 32 + e] = cr[f];
        } else {
            for (int t = tid; t < 1024; t += 256) {
                int e = t & 31, j = t >> 5;
                segT[j * 32 + e] = (j < 16) ? eattr[(size_t)(eb + e) * 16 + j] : 0.f;
            }
        }
        __syncthreads();

        // ---- accumulate GEMM1 over this segment, W1 streamed in 32-row chunks ----
        const int soff = seg_off[seg], slen = seg_len[seg];
        for (int jc = 0; jc < slen; jc += 32) {
            for (int t = tid; t < 1024; t += 256) {
                int r = t >> 5, c4 = (t & 31) * 4;
                int rr = soff + jc + r;
                float4 v;
                if (rr < MLPIN) v = *(const float4*)&W1[(size_t)rr * 128 + c4];
                else { v.x = v.y = v.z = v.w = 0.f; }   // pad rows (seg4)
                *(float4*)&wc[r * 128 + c4] = v;
            }
            __syncthreads();
#pragma unroll 8
            for (int j = 0; j < 32; ++j) {
                float4 a = *(const float4*)&segT[(jc + j) * 32 + e0];
                float4 b = *(const float4*)&wc[j * 128 + k0];
                FMA16(acc, a, b);
            }
            __syncthreads();
        }
    }

    // x1 = silu(acc + b1) -> x1T
#pragma unroll
    for (int l = 0; l < 4; ++l) {
        float bias = b1[k0 + l];
#pragma unroll
        for (int i = 0; i < 4; ++i) {
            float v = acc[i * 4 + l] + bias;
            v = v / (1.f + expf(-v));
            x1T[(k0 + l) * 32 + e0 + i] = v;
        }
    }
    __syncthreads();

    // ---- GEMM2: x2 = silu(x1 @ W2 + b2) ----
#pragma unroll
    for (int i = 0; i < 16; ++i) acc[i] = 0.f;
    for (int jc = 0; jc < 128; jc += 32) {
        for (int t = tid; t < 1024; t += 256) {
            int r = t >> 5, c4 = (t & 31) * 4;
            *(float4*)&wc[r * 128 + c4] = *(const float4*)&W2[(size_t)(jc + r) * 128 + c4];
        }
        __syncthreads();
#pragma unroll 8
        for (int j = 0; j < 32; ++j) {
            float4 a = *(const float4*)&x1T[(jc + j) * 32 + e0];
            float4 b = *(const float4*)&wc[j * 128 + k0];
            FMA16(acc, a, b);
        }
        __syncthreads();
    }
#pragma unroll
    for (int l = 0; l < 4; ++l) {
        float bias = b2[k0 + l];
#pragma unroll
        for (int i = 0; i < 4; ++i) {
            float v = acc[i * 4 + l] + bias;
            v = v / (1.f + expf(-v));
            segT[(k0 + l) * 32 + e0 + i] = v;   // segT reused as x2T
        }
    }
    __syncthreads();

    // ---- GEMM3: msg = x2 @ W3 + b3, three 128-col tiles, fused scatter ----
    float msgv[16];
    for (int kt = 0; kt < 3; ++kt) {
        float m3[16];
#pragma unroll
        for (int i = 0; i < 16; ++i) m3[i] = 0.f;
        for (int jc = 0; jc < 128; jc += 32) {
            for (int t = tid; t < 1024; t += 256) {
                int r = t >> 5, c4 = (t & 31) * 4;
                *(float4*)&wc[r * 128 + c4] =
                    *(const float4*)&W3[(size_t)(jc + r) * 384 + kt * 128 + c4];
            }
            __syncthreads();
#pragma unroll 8
            for (int j = 0; j < 32; ++j) {
                float4 a = *(const float4*)&segT[(jc + j) * 32 + e0];
                float4 b = *(const float4*)&wc[j * 128 + k0];
                FMA16(m3, a, b);
            }
            __syncthreads();
        }
#pragma unroll
        for (int l = 0; l < 4; ++l) {
            float bias = b3[kt * 128 + k0 + l];
#pragma unroll
            for (int i = 0; i < 4; ++i) m3[i * 4 + l] += bias;
        }
        if (kt == 0) {          // msg_h -> h_aggr[row]
#pragma unroll
            for (int i = 0; i < 4; ++i) {
                size_t rb = (size_t)s_row[e0 + i] * 128 + k0;
#pragma unroll
                for (int l = 0; l < 4; ++l) atomicAdd(&hagg[rb + l], m3[i * 4 + l]);
            }
        } else if (kt == 1) {   // msg_v: keep in registers
#pragma unroll
            for (int i = 0; i < 16; ++i) msgv[i] = m3[i];
        } else {                // msg_x: vec_msg = vec3[col]*msg_v + x_ij*msg_x -> dvec[row]
#pragma unroll
            for (int i = 0; i < 4; ++i) {
                const int e = e0 + i;
                const size_t cb = (size_t)s_col[e] * 1152 + 256 + k0;  // vec3[col]
                const size_t rb = (size_t)s_row[e] * 384 + k0;
                const float xj0 = s_xij[e * 3 + 0], xj1 = s_xij[e * 3 + 1], xj2 = s_xij[e * 3 + 2];
#pragma unroll
                for (int l = 0; l < 4; ++l) {
                    float mv = msgv[i * 4 + l], mx = m3[i * 4 + l];
                    atomicAdd(&dvec[rb + l],       vecp[cb + l]       * mv + xj0 * mx);
                    atomicAdd(&dvec[rb + 128 + l], vecp[cb + 384 + l] * mv + xj1 * mx);
                    atomicAdd(&dvec[rb + 256 + l], vecp[cb + 768 + l] * mv + xj2 * mx);
                }
            }
        }
    }
}

// ---------------------------------------------------------------------------
extern "C" void kernel_launch(void* const* d_in, const int* in_sizes, int n_in,
                              void* d_out, int out_size, void* d_ws, size_t ws_size,
                              hipStream_t stream)
{
    const float* h     = (const float*)d_in[0];
    const float* vec   = (const float*)d_in[1];
    const float* coord = (const float*)d_in[2];
    const int*   eidx  = (const int*)  d_in[3];
    const float* eattr = (const float*)d_in[4];
    const float* Wvp   = (const float*)d_in[5];
    const float* W1    = (const float*)d_in[6];
    const float* b1    = (const float*)d_in[7];
    const float* W2    = (const float*)d_in[8];
    const float* b2    = (const float*)d_in[9];
    const float* W3    = (const float*)d_in[10];
    const float* b3    = (const float*)d_in[11];
    const float* Wop   = (const float*)d_in[12];
    const float* bop   = (const float*)d_in[13];

    if (ws_size < WS_FLOATS * sizeof(float)) return;  // need ~358.4 MB scratch

    float* ws   = (float*)d_ws;
    float* vecp = ws + OFF_VECP;
    float* vdot = ws + OFF_VDOT;
    float* hagg = ws + OFF_HAGG;
    float* obuf = ws + OFF_OBUF;
    float* dh   = (float*)d_out;
    float* dvec = (float*)d_out + (size_t)NN * HID;

    dim3 b256(256);
    // 1) vecp = vec @ Wvp     [150000,128] x [128,384]
    gemm128<false><<<dim3(3, 1172), b256, 0, stream>>>(vec, Wvp, nullptr, vecp, 150000);
    // 2) vec_dot + zero h_aggr + zero dvec region
    prep_kernel<<<25000, b256, 0, stream>>>(vecp, vdot, hagg, dvec);
    // 3) fused per-edge MLP + scatter
    edge_kernel<<<12500, b256, 0, stream>>>(h, vecp, coord, eidx, eattr,
                                            W1, b1, W2, b2, W3, b3, hagg, dvec);
    // 4) o = h_aggr @ Wop + bop
    gemm128<true><<<dim3(3, 391), b256, 0, stream>>>(hagg, Wop, bop, obuf, 50000);
    // 5) dh = vdot*o2 + o3 ; dvec += vec3*o1
    fin_kernel<<<25000, b256, 0, stream>>>(vecp, vdot, obuf, dh, dvec);
}

// Round 2
// 2751.498 us; speedup vs baseline: 1.2733x; 1.2733x over previous
//
#include <hip/hip_runtime.h>
#include <math.h>

// Problem constants
constexpr int NN    = 50000;
constexpr int NE    = 400000;
constexpr int HID   = 128;

// Workspace layout (float offsets)
constexpr size_t OFF_VECP = 0;           // [N,3,384]
constexpr size_t OFF_VDOT = 57600000;    // [N,128]
constexpr size_t OFF_HAGG = 64000000;    // [N,128]
constexpr size_t OFF_OBUF = 70400000;    // [N,384]; bf16 weights overlap head (dead before obuf written)
constexpr size_t WS_FLOATS = 89600000;

// bf16 split-weight offsets (in shorts, within OFF_OBUF region)
constexpr size_t O_W1H = 0;        // [128][448]
constexpr size_t O_W1L = 57344;
constexpr size_t O_W2H = 114688;   // [128][128]
constexpr size_t O_W2L = 131072;
constexpr size_t O_W3H = 147456;   // [384][128]
constexpr size_t O_W3L = 196608;
constexpr size_t WT_SHORTS = 245760;

typedef __attribute__((ext_vector_type(8))) short short8;
typedef __attribute__((ext_vector_type(4))) float f32x4;

__device__ __forceinline__ short f2bf_rne(float f) {
    unsigned u = __float_as_uint(f);
    u += 0x7fffu + ((u >> 16) & 1u);
    return (short)(u >> 16);
}
__device__ __forceinline__ float bf2f(short h) {
    return __uint_as_float(((unsigned)(unsigned short)h) << 16);
}
__device__ __forceinline__ void split8(const float* t, short8& ah, short8& al) {
#pragma unroll
    for (int j = 0; j < 8; ++j) {
        short hi = f2bf_rne(t[j]);
        ah[j] = hi;
        al[j] = f2bf_rne(t[j] - bf2f(hi));
    }
}
__device__ __forceinline__ f32x4 mfma3(short8 ah, short8 al, short8 bh, short8 bl, f32x4 c) {
    c = __builtin_amdgcn_mfma_f32_16x16x32_bf16(ah, bh, c, 0, 0, 0);
    c = __builtin_amdgcn_mfma_f32_16x16x32_bf16(al, bh, c, 0, 0, 0);
    c = __builtin_amdgcn_mfma_f32_16x16x32_bf16(ah, bl, c, 0, 0, 0);
    return c;
}

#define VLOAD8(dst, src) do { \
    *(float4*)&(dst)[0] = *(const float4*)(src); \
    *(float4*)&(dst)[4] = *(const float4*)((src) + 4); } while (0)

// ---------------------------------------------------------------------------
// Weight prep: split fp32 weights into (hi,lo) bf16, transposed to [n][k].
// 122880 elements total -> 480 blocks x 256.
// ---------------------------------------------------------------------------
__global__ void wprep_kernel(const float* __restrict__ W1, const float* __restrict__ W2,
                             const float* __restrict__ W3, short* __restrict__ wt)
{
    int idx = blockIdx.x * 256 + threadIdx.x;
    float v; size_t oh, ol;
    if (idx < 57344) {                       // W1t [128n][448k], k<432 valid
        int n = idx / 448, k = idx - n * 448;
        v = (k < 432) ? W1[(size_t)k * 128 + n] : 0.f;
        oh = O_W1H + idx; ol = O_W1L + idx;
    } else if (idx < 73728) {                // W2t [128n][128k]
        int j = idx - 57344; int n = j >> 7, k = j & 127;
        v = W2[(size_t)k * 128 + n];
        oh = O_W2H + j; ol = O_W2L + j;
    } else {                                 // W3t [384n][128k]
        int j = idx - 73728; int n = j >> 7, k = j & 127;
        v = W3[(size_t)k * 384 + n];
        oh = O_W3H + j; ol = O_W3L + j;
    }
    short hi = f2bf_rne(v);
    wt[oh] = hi;
    wt[ol] = f2bf_rne(v - bf2f(hi));
}

// ---------------------------------------------------------------------------
// fp32 GEMM for vecp and obuf (unchanged from R1)
// ---------------------------------------------------------------------------
template<bool BIAS>
__global__ void __launch_bounds__(256, 2)
gemm128(const float* __restrict__ A, const float* __restrict__ B,
        const float* __restrict__ bias, float* __restrict__ C, int M)
{
    __shared__ __align__(16) float As[16 * 132];
    __shared__ __align__(16) float Bs[16 * 132];
    const int tid = threadIdx.x;
    const int m0 = blockIdx.y * 128;
    const int n0 = blockIdx.x * 128;
    const int ty = tid >> 4, tx = tid & 15;

    float acc[64];
#pragma unroll
    for (int i = 0; i < 64; ++i) acc[i] = 0.f;

    for (int kc = 0; kc < 128; kc += 16) {
#pragma unroll
        for (int p = 0; p < 2; ++p) {
            int mm = (tid >> 2) + p * 64;
            int kq = (tid & 3) * 4;
            int mr = (m0 + mm < M) ? (m0 + mm) : 0;
            float4 v = *(const float4*)&A[(size_t)mr * 128 + kc + kq];
            As[(kq + 0) * 132 + mm] = v.x; As[(kq + 1) * 132 + mm] = v.y;
            As[(kq + 2) * 132 + mm] = v.z; As[(kq + 3) * 132 + mm] = v.w;
        }
#pragma unroll
        for (int p = 0; p < 2; ++p) {
            int t = tid + p * 256;
            int k = t >> 5, c4 = (t & 31) * 4;
            *(float4*)&Bs[k * 132 + c4] =
                *(const float4*)&B[(size_t)(kc + k) * 384 + n0 + c4];
        }
        __syncthreads();
#pragma unroll
        for (int kk = 0; kk < 16; ++kk) {
            float a[8], b[8];
            *(float4*)&a[0] = *(const float4*)&As[kk * 132 + ty * 8];
            *(float4*)&a[4] = *(const float4*)&As[kk * 132 + ty * 8 + 4];
            *(float4*)&b[0] = *(const float4*)&Bs[kk * 132 + tx * 8];
            *(float4*)&b[4] = *(const float4*)&Bs[kk * 132 + tx * 8 + 4];
#pragma unroll
            for (int i = 0; i < 8; ++i)
#pragma unroll
                for (int j = 0; j < 8; ++j) acc[i * 8 + j] += a[i] * b[j];
        }
        __syncthreads();
    }
#pragma unroll
    for (int i = 0; i < 8; ++i) {
        int mm = m0 + ty * 8 + i;
        if (mm < M) {
            float o0[4], o1[4];
#pragma unroll
            for (int j = 0; j < 4; ++j) {
                float v0 = acc[i * 8 + j], v1 = acc[i * 8 + 4 + j];
                if (BIAS) {
                    v0 += bias[n0 + tx * 8 + j];
                    v1 += bias[n0 + tx * 8 + 4 + j];
                }
                o0[j] = v0; o1[j] = v1;
            }
            float* dst = &C[(size_t)mm * 384 + n0 + tx * 8];
            *(float4*)dst       = *(float4*)o0;
            *(float4*)(dst + 4) = *(float4*)o1;
        }
    }
}

__global__ void prep_kernel(const float* __restrict__ vecp, float* __restrict__ vdot,
                            float* __restrict__ hagg, float* __restrict__ dvec)
{
    int idx = blockIdx.x * 256 + threadIdx.x;
    int n = idx >> 7, k = idx & 127;
    size_t b = (size_t)n * 1152;
    float s = vecp[b + k]       * vecp[b + 128 + k]
            + vecp[b + 384 + k] * vecp[b + 512 + k]
            + vecp[b + 768 + k] * vecp[b + 896 + k];
    vdot[idx] = s;
    hagg[idx] = 0.f;
    size_t db = (size_t)n * 384 + k;
    dvec[db] = 0.f; dvec[db + 128] = 0.f; dvec[db + 256] = 0.f;
}

__global__ void fin_kernel(const float* __restrict__ vecp, const float* __restrict__ vdot,
                           const float* __restrict__ obuf, float* __restrict__ dh,
                           float* __restrict__ dvec)
{
    int idx = blockIdx.x * 256 + threadIdx.x;
    int n = idx >> 7, k = idx & 127;
    const float* o = obuf + (size_t)n * 384;
    float o1 = o[k], o2 = o[128 + k], o3 = o[256 + k];
    dh[idx] = vdot[idx] * o2 + o3;
    size_t vb = (size_t)n * 1152 + 256 + k;
    size_t db = (size_t)n * 384 + k;
    dvec[db]       += vecp[vb]       * o1;
    dvec[db + 128] += vecp[vb + 384] * o1;
    dvec[db + 256] += vecp[vb + 768] * o1;
}

// ---------------------------------------------------------------------------
// Fused edge kernel, split-bf16 MFMA. 64 edges/block, 4 independent waves of
// 16 edges. A-frags gathered straight from global into registers; weights
// (pre-split, [n][k]) read from L2; only x1/x2 layout transform uses LDS.
// mlp_in k-layout: [h_row 0-127 | h_col 128-255 | rbf 256-287 | cross 288-415
//                   | eattr 416-431 | pad 432-447]  -> 14 k-steps of 32.
// ---------------------------------------------------------------------------
__global__ void __launch_bounds__(256, 3)
edge_kernel(const float* __restrict__ h, const float* __restrict__ vecp,
            const float* __restrict__ coord, const int* __restrict__ eidx,
            const float* __restrict__ eattr, const short* __restrict__ wt,
            const float* __restrict__ b1, const float* __restrict__ b2,
            const float* __restrict__ b3,
            float* __restrict__ hagg, float* __restrict__ dvec)
{
    __shared__ short xh[64][136];   // x1/x2 hi, [edge][k], +8 pad
    __shared__ short xl[64][136];   // x1/x2 lo
    __shared__ int   s_row[64], s_col[64];
    __shared__ float s_xij[64][3];
    __shared__ float s_d[64];

    const short* W1h = wt + O_W1H; const short* W1l = wt + O_W1L;
    const short* W2h = wt + O_W2H; const short* W2l = wt + O_W2L;
    const short* W3h = wt + O_W3H; const short* W3l = wt + O_W3L;

    const int tid  = threadIdx.x;
    const int wave = tid >> 6, lane = tid & 63;
    const int m  = lane & 15;       // A: edge-in-tile / B,C,D: column-in-tile
    const int kg = lane >> 4;       // k-group (8 elements each)
    const int et = wave * 16;       // this wave's local edge base
    const int el = et + m;          // local edge for A-frag rows
    const int eb = blockIdx.x * 64; // global edge base (E = 6250*64 exactly)

    if (tid < 64) {
        int r = eidx[eb + tid], c = eidx[NE + eb + tid];
        s_row[tid] = r; s_col[tid] = c;
        float x0 = coord[r * 3 + 0] - coord[c * 3 + 0];
        float x1 = coord[r * 3 + 1] - coord[c * 3 + 1];
        float x2 = coord[r * 3 + 2] - coord[c * 3 + 2];
        s_xij[tid][0] = x0; s_xij[tid][1] = x1; s_xij[tid][2] = x2;
        s_d[tid] = sqrtf(x0 * x0 + x1 * x1 + x2 * x2 + 1e-8f);
    }
    __syncthreads();

    const int rowm = s_row[el], colm = s_col[el];
    const f32x4 zf = {0.f, 0.f, 0.f, 0.f};

    // ---------------- GEMM1: [16e x 448] @ W1t -> x1 [16e x 128] ----------
    f32x4 acc[8];
#pragma unroll
    for (int t = 0; t < 8; ++t) acc[t] = zf;

    for (int ks = 0; ks < 14; ++ks) {
        float tmp[8];
        if (ks < 4) {
            VLOAD8(tmp, h + (size_t)rowm * 128 + ks * 32 + kg * 8);
        } else if (ks < 8) {
            VLOAD8(tmp, h + (size_t)colm * 128 + (ks - 4) * 32 + kg * 8);
        } else if (ks == 8) {
            const float delta = 5.0f / 31.0f;
            const float coeff = -0.5f / (delta * delta);
            float dd = s_d[el]; int kk = kg * 8;
#pragma unroll
            for (int j = 0; j < 8; ++j) {
                float x = dd - (float)(kk + j) * delta;
                tmp[j] = __expf(coeff * x * x);
            }
        } else if (ks < 13) {
            int kk = (ks - 9) * 32 + kg * 8;
            const float* vr = vecp + (size_t)rowm * 1152 + kk;         // vec1[row]
            const float* vc = vecp + (size_t)colm * 1152 + 128 + kk;   // vec2[col]
            float t0[8], t1[8];
            VLOAD8(t0, vr);       VLOAD8(t1, vc);
#pragma unroll
            for (int j = 0; j < 8; ++j) tmp[j] = t0[j] * t1[j];
            VLOAD8(t0, vr + 384); VLOAD8(t1, vc + 384);
#pragma unroll
            for (int j = 0; j < 8; ++j) tmp[j] += t0[j] * t1[j];
            VLOAD8(t0, vr + 768); VLOAD8(t1, vc + 768);
#pragma unroll
            for (int j = 0; j < 8; ++j) tmp[j] += t0[j] * t1[j];
        } else {
            if (kg < 2) { VLOAD8(tmp, eattr + (size_t)(eb + el) * 16 + kg * 8); }
            else {
#pragma unroll
                for (int j = 0; j < 8; ++j) tmp[j] = 0.f;
            }
        }
        short8 ah, al; split8(tmp, ah, al);
        const int kc = ks * 32 + kg * 8;
#pragma unroll
        for (int t = 0; t < 8; ++t) {
            const short* p = W1h + (size_t)(t * 16 + m) * 448 + kc;
            const short* q = W1l + (size_t)(t * 16 + m) * 448 + kc;
            acc[t] = mfma3(ah, al, *(const short8*)p, *(const short8*)q, acc[t]);
        }
    }
    // epilogue: silu, split, store to LDS in [e][k] layout
#pragma unroll
    for (int t = 0; t < 8; ++t) {
        float bias = b1[t * 16 + m];
#pragma unroll
        for (int r = 0; r < 4; ++r) {
            float v = acc[t][r] + bias;
            float sv = v * __builtin_amdgcn_rcpf(1.f + __expf(-v));
            short hi = f2bf_rne(sv);
            int er = et + kg * 4 + r;
            xh[er][t * 16 + m] = hi;
            xl[er][t * 16 + m] = f2bf_rne(sv - bf2f(hi));
        }
    }
    __syncthreads();

    // ---------------- GEMM2: x1 @ W2t -> x2 [16e x 128] -------------------
#pragma unroll
    for (int t = 0; t < 8; ++t) acc[t] = zf;
    for (int ks = 0; ks < 4; ++ks) {
        const int kc = ks * 32 + kg * 8;
        short8 ah = *(const short8*)&xh[el][kc];
        short8 al = *(const short8*)&xl[el][kc];
#pragma unroll
        for (int t = 0; t < 8; ++t) {
            const short* p = W2h + (size_t)(t * 16 + m) * 128 + kc;
            const short* q = W2l + (size_t)(t * 16 + m) * 128 + kc;
            acc[t] = mfma3(ah, al, *(const short8*)p, *(const short8*)q, acc[t]);
        }
    }
#pragma unroll
    for (int t = 0; t < 8; ++t) {
        float bias = b2[t * 16 + m];
#pragma unroll
        for (int r = 0; r < 4; ++r) {
            float v = acc[t][r] + bias;
            float sv = v * __builtin_amdgcn_rcpf(1.f + __expf(-v));
            short hi = f2bf_rne(sv);
            int er = et + kg * 4 + r;
            xh[er][t * 16 + m] = hi;
            xl[er][t * 16 + m] = f2bf_rne(sv - bf2f(hi));
        }
    }
    __syncthreads();

    // ---------------- GEMM3: x2 @ W3t -> msg [16e x 384], fused scatter ----
    int rows4[4], col4[4]; float xijv[4][3];
#pragma unroll
    for (int r = 0; r < 4; ++r) {
        int er = et + kg * 4 + r;
        rows4[r] = s_row[er]; col4[r] = s_col[er];
        xijv[r][0] = s_xij[er][0]; xijv[r][1] = s_xij[er][1]; xijv[r][2] = s_xij[er][2];
    }
    float msgv[32];
    for (int c = 0; c < 3; ++c) {
        f32x4 a3[8];
#pragma unroll
        for (int t = 0; t < 8; ++t) a3[t] = zf;
        for (int ks = 0; ks < 4; ++ks) {
            const int kc = ks * 32 + kg * 8;
            short8 ah = *(const short8*)&xh[el][kc];
            short8 al = *(const short8*)&xl[el][kc];
#pragma unroll
            for (int t = 0; t < 8; ++t) {
                const short* p = W3h + (size_t)(c * 128 + t * 16 + m) * 128 + kc;
                const short* q = W3l + (size_t)(c * 128 + t * 16 + m) * 128 + kc;
                a3[t] = mfma3(ah, al, *(const short8*)p, *(const short8*)q, a3[t]);
            }
        }
        if (c == 0) {          // msg_h -> h_aggr[row]
#pragma unroll
            for (int t = 0; t < 8; ++t) {
                float bias = b3[t * 16 + m];
#pragma unroll
                for (int r = 0; r < 4; ++r)
                    atomicAdd(&hagg[(size_t)rows4[r] * 128 + t * 16 + m], a3[t][r] + bias);
            }
        } else if (c == 1) {   // msg_v: keep
#pragma unroll
            for (int t = 0; t < 8; ++t) {
                float bias = b3[128 + t * 16 + m];
#pragma unroll
                for (int r = 0; r < 4; ++r) msgv[t * 4 + r] = a3[t][r] + bias;
            }
        } else {               // msg_x: vec_msg = vec3[col]*msg_v + x_ij*msg_x
#pragma unroll
            for (int t = 0; t < 8; ++t) {
                float bias = b3[256 + t * 16 + m];
#pragma unroll
                for (int r = 0; r < 4; ++r) {
                    float mx = a3[t][r] + bias;
                    float mv = msgv[t * 4 + r];
                    const float* v3 = vecp + (size_t)col4[r] * 1152 + 256 + t * 16 + m;
                    float* dst = dvec + (size_t)rows4[r] * 384 + t * 16 + m;
                    atomicAdd(dst,       v3[0]   * mv + xijv[r][0] * mx);
                    atomicAdd(dst + 128, v3[384] * mv + xijv[r][1] * mx);
                    atomicAdd(dst + 256, v3[768] * mv + xijv[r][2] * mx);
                }
            }
        }
    }
}

// ---------------------------------------------------------------------------
extern "C" void kernel_launch(void* const* d_in, const int* in_sizes, int n_in,
                              void* d_out, int out_size, void* d_ws, size_t ws_size,
                              hipStream_t stream)
{
    const float* h     = (const float*)d_in[0];
    const float* vec   = (const float*)d_in[1];
    const float* coord = (const float*)d_in[2];
    const int*   eidx  = (const int*)  d_in[3];
    const float* eattr = (const float*)d_in[4];
    const float* Wvp   = (const float*)d_in[5];
    const float* W1    = (const float*)d_in[6];
    const float* b1    = (const float*)d_in[7];
    const float* W2    = (const float*)d_in[8];
    const float* b2    = (const float*)d_in[9];
    const float* W3    = (const float*)d_in[10];
    const float* b3    = (const float*)d_in[11];
    const float* Wop   = (const float*)d_in[12];
    const float* bop   = (const float*)d_in[13];

    if (ws_size < WS_FLOATS * sizeof(float)) return;

    float* ws   = (float*)d_ws;
    float* vecp = ws + OFF_VECP;
    float* vdot = ws + OFF_VDOT;
    float* hagg = ws + OFF_HAGG;
    float* obuf = ws + OFF_OBUF;
    short* wt   = (short*)(ws + OFF_OBUF);   // weights dead before obuf written
    float* dh   = (float*)d_out;
    float* dvec = (float*)d_out + (size_t)NN * HID;

    dim3 b256(256);
    // 0) split/transpose MLP weights to bf16 hi/lo
    wprep_kernel<<<480, b256, 0, stream>>>(W1, W2, W3, wt);
    // 1) vecp = vec @ Wvp   (fp32: feeds vdot/cross/vec3, keep full precision)
    gemm128<false><<<dim3(3, 1172), b256, 0, stream>>>(vec, Wvp, nullptr, vecp, 150000);
    // 2) vec_dot + zero h_aggr + zero dvec region
    prep_kernel<<<25000, b256, 0, stream>>>(vecp, vdot, hagg, dvec);
    // 3) fused per-edge MLP (split-bf16 MFMA) + scatter
    edge_kernel<<<6250, b256, 0, stream>>>(h, vecp, coord, eidx, eattr, wt,
                                           b1, b2, b3, hagg, dvec);
    // 4) o = h_aggr @ Wop + bop
    gemm128<true><<<dim3(3, 391), b256, 0, stream>>>(hagg, Wop, bop, obuf, 50000);
    // 5) dh = vdot*o2 + o3 ; dvec += vec3*o1
    fin_kernel<<<25000, b256, 0, stream>>>(vecp, vdot, obuf, dh, dvec);
}

// Round 3
// 1813.162 us; speedup vs baseline: 1.9323x; 1.5175x over previous
//
#include <hip/hip_runtime.h>
#include <math.h>

// Problem constants
constexpr int NN    = 50000;
constexpr int NE    = 400000;
constexpr int HID   = 128;

// Workspace layout (float offsets). hw dead after edge_kernel; obuf overlaps it.
constexpr size_t OFF_VECP = 0;            // [N,3,384]   57.6M
constexpr size_t OFF_HAGG = 57600000;     // [N,128]      6.4M
constexpr size_t OFF_HW   = 64000000;     // [N,256]     12.8M (dead after edge)
constexpr size_t OFF_OBUF = 64000000;     // [N,384]     19.2M (after edge)
constexpr size_t OFF_WT   = 83200000;     // weights, 221184*2 shorts
constexpr size_t WS_FLOATS = 83431184;

// split-bf16 weight offsets (shorts, within wt region)
constexpr size_t O_HWH = 0;        // [256n][128k]  h-part of W1 (rows 0..255)
constexpr size_t O_HWL = 32768;
constexpr size_t O_W1H = 65536;    // [128n][192k]  cross|rbf|eattr|pad
constexpr size_t O_W1L = 90112;
constexpr size_t O_W2H = 114688;   // [128n][128k]
constexpr size_t O_W2L = 131072;
constexpr size_t O_W3H = 147456;   // [384n][128k]
constexpr size_t O_W3L = 196608;
constexpr size_t O_VPH = 245760;   // [384n][128k]  Wvp^T
constexpr size_t O_VPL = 294912;
constexpr size_t O_OPH = 344064;   // [384n][128k]  Wop^T
constexpr size_t O_OPL = 393216;
constexpr size_t WT_SHORTS = 442368;

typedef __attribute__((ext_vector_type(8))) short short8;
typedef __attribute__((ext_vector_type(4))) float f32x4;

__device__ __forceinline__ short f2bf_rne(float f) {
    unsigned u = __float_as_uint(f);
    u += 0x7fffu + ((u >> 16) & 1u);
    return (short)(u >> 16);
}
__device__ __forceinline__ float bf2f(short h) {
    return __uint_as_float(((unsigned)(unsigned short)h) << 16);
}
__device__ __forceinline__ void split8(const float* t, short8& ah, short8& al) {
#pragma unroll
    for (int j = 0; j < 8; ++j) {
        short hi = f2bf_rne(t[j]);
        ah[j] = hi;
        al[j] = f2bf_rne(t[j] - bf2f(hi));
    }
}
__device__ __forceinline__ f32x4 mfma3(short8 ah, short8 al, short8 bh, short8 bl, f32x4 c) {
    c = __builtin_amdgcn_mfma_f32_16x16x32_bf16(ah, bh, c, 0, 0, 0);
    c = __builtin_amdgcn_mfma_f32_16x16x32_bf16(al, bh, c, 0, 0, 0);
    c = __builtin_amdgcn_mfma_f32_16x16x32_bf16(ah, bl, c, 0, 0, 0);
    return c;
}

#define VLOAD8(dst, src) do { \
    *(float4*)&(dst)[0] = *(const float4*)(src); \
    *(float4*)&(dst)[4] = *(const float4*)((src) + 4); } while (0)

// ---------------------------------------------------------------------------
// Weight prep: all weights -> split bf16 hi/lo, transposed to [n][k].
// 221184 elements = 864 * 256.
// ---------------------------------------------------------------------------
__global__ void wprep_kernel(const float* __restrict__ W1, const float* __restrict__ W2,
                             const float* __restrict__ W3, const float* __restrict__ Wvp,
                             const float* __restrict__ Wop, short* __restrict__ wt)
{
    int idx = blockIdx.x * 256 + threadIdx.x;
    float v; size_t oh, ol;
    if (idx < 32768) {                        // hw: [256][128], W1 rows 0..255
        int j = idx >> 7, k = idx & 127;
        v = (j < 128) ? W1[(size_t)k * 128 + j] : W1[(size_t)(128 + k) * 128 + (j - 128)];
        oh = O_HWH + idx; ol = O_HWL + idx;
    } else if (idx < 57344) {                 // W1cde: [128][192]
        int l = idx - 32768; int n = l / 192, k = l - n * 192;
        int r = (k < 128) ? (288 + k) : (k < 160) ? (256 + k - 128) : (k < 176) ? (416 + k - 160) : -1;
        v = (r < 0) ? 0.f : W1[(size_t)r * 128 + n];
        oh = O_W1H + l; ol = O_W1L + l;
    } else if (idx < 73728) {                 // W2t [128][128]
        int l = idx - 57344; int n = l >> 7, k = l & 127;
        v = W2[(size_t)k * 128 + n];
        oh = O_W2H + l; ol = O_W2L + l;
    } else if (idx < 122880) {                // W3t [384][128]
        int l = idx - 73728; int n = l >> 7, k = l & 127;
        v = W3[(size_t)k * 384 + n];
        oh = O_W3H + l; ol = O_W3L + l;
    } else if (idx < 172032) {                // Wvpt [384][128]
        int l = idx - 122880; int n = l >> 7, k = l & 127;
        v = Wvp[(size_t)k * 384 + n];
        oh = O_VPH + l; ol = O_VPL + l;
    } else {                                  // Wopt [384][128]
        int l = idx - 172032; int n = l >> 7, k = l & 127;
        v = Wop[(size_t)k * 384 + n];
        oh = O_OPH + l; ol = O_OPL + l;
    }
    short hi = f2bf_rne(v);
    wt[oh] = hi;
    wt[ol] = f2bf_rne(v - bf2f(hi));
}

// ---------------------------------------------------------------------------
// Node GEMM: C[M, NT*64] = A[M,128] @ Wt^T (+bias), split-bf16 MFMA.
// Block 256 thr / 4 waves; M-tile 32 (2 sub-tiles of 16); wave owns NT*16 cols.
// ---------------------------------------------------------------------------
template<int NT>
__global__ void __launch_bounds__(256, 3)
gemm_node(const float* __restrict__ A, int M,
          const short* __restrict__ wh, const short* __restrict__ wl,
          float* __restrict__ C, const float* __restrict__ bias)
{
    const int N = NT * 64;
    const int tid = threadIdx.x, wave = tid >> 6, lane = tid & 63;
    const int m = lane & 15, kg = lane >> 4;
    const int gm0 = blockIdx.x * 32;
    const int nb = wave * NT * 16;
    const f32x4 zf = {0.f, 0.f, 0.f, 0.f};
    f32x4 acc[2][NT];
#pragma unroll
    for (int mt = 0; mt < 2; ++mt)
#pragma unroll
        for (int tt = 0; tt < NT; ++tt) acc[mt][tt] = zf;

    for (int ks = 0; ks < 4; ++ks) {
        short8 ah[2], al[2];
#pragma unroll
        for (int mt = 0; mt < 2; ++mt) {
            int r = gm0 + mt * 16 + m;
            if (r >= M) r = M - 1;
            float tmp[8];
            VLOAD8(tmp, A + (size_t)r * 128 + ks * 32 + kg * 8);
            split8(tmp, ah[mt], al[mt]);
        }
#pragma unroll
        for (int tt = 0; tt < NT; ++tt) {
            size_t wo = (size_t)(nb + tt * 16 + m) * 128 + ks * 32 + kg * 8;
            short8 bh = *(const short8*)(wh + wo);
            short8 bl = *(const short8*)(wl + wo);
#pragma unroll
            for (int mt = 0; mt < 2; ++mt)
                acc[mt][tt] = mfma3(ah[mt], al[mt], bh, bl, acc[mt][tt]);
        }
    }
    float bv[NT];
#pragma unroll
    for (int tt = 0; tt < NT; ++tt) bv[tt] = bias ? bias[nb + tt * 16 + m] : 0.f;
#pragma unroll
    for (int mt = 0; mt < 2; ++mt)
#pragma unroll
        for (int r = 0; r < 4; ++r) {
            int row = gm0 + mt * 16 + kg * 4 + r;
            if (row < M) {
#pragma unroll
                for (int tt = 0; tt < NT; ++tt)
                    C[(size_t)row * N + nb + tt * 16 + m] = acc[mt][tt][r] + bv[tt];
            }
        }
}

// ---------------------------------------------------------------------------
// prep: zero h_aggr and the dvec region of d_out (both re-poisoned each call)
// ---------------------------------------------------------------------------
__global__ void prep_kernel(float* __restrict__ hagg, float* __restrict__ dvec)
{
    int idx = blockIdx.x * 256 + threadIdx.x;   // N*128 threads
    int n = idx >> 7, k = idx & 127;
    hagg[idx] = 0.f;
    size_t db = (size_t)n * 384 + k;
    dvec[db] = 0.f; dvec[db + 128] = 0.f; dvec[db + 256] = 0.f;
}

// ---------------------------------------------------------------------------
// finalize: vdot recomputed inline; dh = vdot*o2 + o3; dvec += vec3*o1
// ---------------------------------------------------------------------------
__global__ void fin_kernel(const float* __restrict__ vecp, const float* __restrict__ obuf,
                           float* __restrict__ dh, float* __restrict__ dvec)
{
    int idx = blockIdx.x * 256 + threadIdx.x;
    int n = idx >> 7, k = idx & 127;
    size_t b = (size_t)n * 1152;
    float vd = vecp[b + k]       * vecp[b + 128 + k]
             + vecp[b + 384 + k] * vecp[b + 512 + k]
             + vecp[b + 768 + k] * vecp[b + 896 + k];
    const float* o = obuf + (size_t)n * 384;
    float o1 = o[k], o2 = o[128 + k], o3 = o[256 + k];
    dh[idx] = vd * o2 + o3;
    size_t vb = b + 256 + k;
    size_t db = (size_t)n * 384 + k;
    dvec[db]       += vecp[vb]       * o1;
    dvec[db + 128] += vecp[vb + 384] * o1;
    dvec[db + 256] += vecp[vb + 768] * o1;
}

// ---------------------------------------------------------------------------
// Fused edge kernel. 64 edges/block, 256 thr / 4 waves. Wave owns 32 N-cols,
// loops 4 M-tiles (B-frag reuse x4). GEMM1 K=192: cross(128)|rbf(32)|eattr+pad;
// A-chunks built cooperatively into double-buffered LDS one k-step ahead.
// h-contribution comes pre-multiplied via hw[row]/hw[col] gathers (C-init).
// LDS ~57KB -> 2 blocks/CU.
// ---------------------------------------------------------------------------
__global__ void __launch_bounds__(256, 2)
edge_kernel(const float* __restrict__ vecp, const float* __restrict__ hw,
            const float* __restrict__ coord, const int* __restrict__ eidx,
            const float* __restrict__ eattr, const short* __restrict__ wt,
            const float* __restrict__ b1, const float* __restrict__ b2,
            const float* __restrict__ b3,
            float* __restrict__ hagg, float* __restrict__ dvec)
{
    __shared__ __align__(16) short abh[2][64][40];  // A chunk hi, [buf][edge][k]
    __shared__ __align__(16) short abl[2][64][40];  // A chunk lo
    __shared__ __align__(16) short xh[64][136];     // x1/x2 hi, [edge][k]
    __shared__ __align__(16) short xl[64][136];
    __shared__ int   s_row[64], s_col[64];
    __shared__ float s_xij[64][3];
    __shared__ float s_d[64];

    const int tid = threadIdx.x;
    const int wave = tid >> 6, lane = tid & 63;
    const int m = lane & 15, kg = lane >> 4;
    const int nb = wave * 32;          // this wave's N-base (cols)
    const int eb = blockIdx.x * 64;    // E = 6250*64 exactly
    const int be = tid >> 2;           // build: edge 0..63
    const int bq = (tid & 3) * 8;      // build: k-offset in chunk {0,8,16,24}

    if (tid < 64) {
        int r = eidx[eb + tid], c = eidx[NE + eb + tid];
        s_row[tid] = r; s_col[tid] = c;
        float x0 = coord[r * 3 + 0] - coord[c * 3 + 0];
        float x1 = coord[r * 3 + 1] - coord[c * 3 + 1];
        float x2 = coord[r * 3 + 2] - coord[c * 3 + 2];
        s_xij[tid][0] = x0; s_xij[tid][1] = x1; s_xij[tid][2] = x2;
        s_d[tid] = sqrtf(x0 * x0 + x1 * x1 + x2 * x2 + 1e-8f);
    }
    __syncthreads();

    const f32x4 zf = {0.f, 0.f, 0.f, 0.f};
    const float delta = 5.0f / 31.0f;
    const float coeff = -0.5f / (delta * delta);
    const int brow = s_row[be], bcol = s_col[be];

    // ---- A-chunk builder (one chunk of 32 k for all 64 edges) ----
    auto build = [&](int ks) {
        float tmp[8];
        if (ks < 4) {                      // cross, k in [0,128)
            int kk = ks * 32 + bq;
            const float* vr = vecp + (size_t)brow * 1152 + kk;
            const float* vc = vecp + (size_t)bcol * 1152 + 128 + kk;
            float t0[8], t1[8];
            VLOAD8(t0, vr);       VLOAD8(t1, vc);
#pragma unroll
            for (int j = 0; j < 8; ++j) tmp[j] = t0[j] * t1[j];
            VLOAD8(t0, vr + 384); VLOAD8(t1, vc + 384);
#pragma unroll
            for (int j = 0; j < 8; ++j) tmp[j] += t0[j] * t1[j];
            VLOAD8(t0, vr + 768); VLOAD8(t1, vc + 768);
#pragma unroll
            for (int j = 0; j < 8; ++j) tmp[j] += t0[j] * t1[j];
        } else if (ks == 4) {              // rbf, 32 centers
            float dd = s_d[be];
#pragma unroll
            for (int j = 0; j < 8; ++j) {
                float x = dd - (float)(bq + j) * delta;
                tmp[j] = __expf(coeff * x * x);
            }
        } else {                           // eattr (16) + pad (16)
            if (bq < 16) { VLOAD8(tmp, eattr + (size_t)(eb + be) * 16 + bq); }
            else {
#pragma unroll
                for (int j = 0; j < 8; ++j) tmp[j] = 0.f;
            }
        }
        short8 sh, sl; split8(tmp, sh, sl);
        *(short8*)&abh[ks & 1][be][bq] = sh;
        *(short8*)&abl[ks & 1][be][bq] = sl;
    };

    // ---------------- GEMM1: [64e x 192] @ W1cde -> acc ----------------
    f32x4 acc[4][2];
#pragma unroll
    for (int mt = 0; mt < 4; ++mt) { acc[mt][0] = zf; acc[mt][1] = zf; }

    build(0);
    __syncthreads();
    for (int ks = 0; ks < 6; ++ks) {
        if (ks < 5) build(ks + 1);         // prefetch next chunk (other buffer)
        short8 ah4[4], al4[4];
#pragma unroll
        for (int mt = 0; mt < 4; ++mt) {
            ah4[mt] = *(const short8*)&abh[ks & 1][mt * 16 + m][kg * 8];
            al4[mt] = *(const short8*)&abl[ks & 1][mt * 16 + m][kg * 8];
        }
#pragma unroll
        for (int tt = 0; tt < 2; ++tt) {
            size_t wo = (size_t)(nb + tt * 16 + m) * 192 + ks * 32 + kg * 8;
            short8 bh = *(const short8*)(wt + O_W1H + wo);
            short8 bl = *(const short8*)(wt + O_W1L + wo);
#pragma unroll
            for (int mt = 0; mt < 4; ++mt)
                acc[mt][tt] = mfma3(ah4[mt], al4[mt], bh, bl, acc[mt][tt]);
        }
        __syncthreads();
    }

    // epilogue1: += hw[row] + hw[col] + b1, silu, split -> xh/xl
    {
        float b1v[2] = { b1[nb + m], b1[nb + 16 + m] };
#pragma unroll
        for (int mt = 0; mt < 4; ++mt)
#pragma unroll
            for (int r = 0; r < 4; ++r) {
                int e = mt * 16 + kg * 4 + r;
                const float* hr = hw + (size_t)s_row[e] * 256;
                const float* hc = hw + (size_t)s_col[e] * 256 + 128;
#pragma unroll
                for (int tt = 0; tt < 2; ++tt) {
                    int n = nb + tt * 16 + m;
                    float v = acc[mt][tt][r] + hr[n] + hc[n] + b1v[tt];
                    float sv = v * __builtin_amdgcn_rcpf(1.f + __expf(-v));
                    short hi = f2bf_rne(sv);
                    xh[e][n] = hi;
                    xl[e][n] = f2bf_rne(sv - bf2f(hi));
                }
            }
    }
    __syncthreads();

    // ---------------- GEMM2: x1 @ W2t -> x2 ----------------
#pragma unroll
    for (int mt = 0; mt < 4; ++mt) { acc[mt][0] = zf; acc[mt][1] = zf; }
    for (int ks = 0; ks < 4; ++ks) {
        short8 ah4[4], al4[4];
#pragma unroll
        for (int mt = 0; mt < 4; ++mt) {
            ah4[mt] = *(const short8*)&xh[mt * 16 + m][ks * 32 + kg * 8];
            al4[mt] = *(const short8*)&xl[mt * 16 + m][ks * 32 + kg * 8];
        }
#pragma unroll
        for (int tt = 0; tt < 2; ++tt) {
            size_t wo = (size_t)(nb + tt * 16 + m) * 128 + ks * 32 + kg * 8;
            short8 bh = *(const short8*)(wt + O_W2H + wo);
            short8 bl = *(const short8*)(wt + O_W2L + wo);
#pragma unroll
            for (int mt = 0; mt < 4; ++mt)
                acc[mt][tt] = mfma3(ah4[mt], al4[mt], bh, bl, acc[mt][tt]);
        }
    }
    {
        float b2v[2] = { b2[nb + m], b2[nb + 16 + m] };
#pragma unroll
        for (int mt = 0; mt < 4; ++mt)
#pragma unroll
            for (int tt = 0; tt < 2; ++tt)
#pragma unroll
                for (int r = 0; r < 4; ++r) {
                    float v = acc[mt][tt][r] + b2v[tt];
                    acc[mt][tt][r] = v * __builtin_amdgcn_rcpf(1.f + __expf(-v));
                }
    }
    __syncthreads();   // all waves done reading x1
#pragma unroll
    for (int mt = 0; mt < 4; ++mt)
#pragma unroll
        for (int tt = 0; tt < 2; ++tt)
#pragma unroll
            for (int r = 0; r < 4; ++r) {
                int e = mt * 16 + kg * 4 + r;
                int n = nb + tt * 16 + m;
                float sv = acc[mt][tt][r];
                short hi = f2bf_rne(sv);
                xh[e][n] = hi;
                xl[e][n] = f2bf_rne(sv - bf2f(hi));
            }
    __syncthreads();

    // ---------------- GEMM3: x2 @ W3t (3 col-tiles) + fused scatter ----
    float msgv[4][2][4];
    for (int c = 0; c < 3; ++c) {
        f32x4 a3[4][2];
#pragma unroll
        for (int mt = 0; mt < 4; ++mt) { a3[mt][0] = zf; a3[mt][1] = zf; }
        for (int ks = 0; ks < 4; ++ks) {
            short8 ah4[4], al4[4];
#pragma unroll
            for (int mt = 0; mt < 4; ++mt) {
                ah4[mt] = *(const short8*)&xh[mt * 16 + m][ks * 32 + kg * 8];
                al4[mt] = *(const short8*)&xl[mt * 16 + m][ks * 32 + kg * 8];
            }
#pragma unroll
            for (int tt = 0; tt < 2; ++tt) {
                size_t wo = (size_t)(c * 128 + nb + tt * 16 + m) * 128 + ks * 32 + kg * 8;
                short8 bh = *(const short8*)(wt + O_W3H + wo);
                short8 bl = *(const short8*)(wt + O_W3L + wo);
#pragma unroll
                for (int mt = 0; mt < 4; ++mt)
                    a3[mt][tt] = mfma3(ah4[mt], al4[mt], bh, bl, a3[mt][tt]);
            }
        }
        float bv[2] = { b3[c * 128 + nb + m], b3[c * 128 + nb + 16 + m] };
        if (c == 0) {          // msg_h -> h_aggr[row]
#pragma unroll
            for (int mt = 0; mt < 4; ++mt)
#pragma unroll
                for (int r = 0; r < 4; ++r) {
                    int e = mt * 16 + kg * 4 + r;
                    size_t rb = (size_t)s_row[e] * 128;
#pragma unroll
                    for (int tt = 0; tt < 2; ++tt)
                        atomicAdd(&hagg[rb + nb + tt * 16 + m], a3[mt][tt][r] + bv[tt]);
                }
        } else if (c == 1) {   // msg_v: keep in registers
#pragma unroll
            for (int mt = 0; mt < 4; ++mt)
#pragma unroll
                for (int tt = 0; tt < 2; ++tt)
#pragma unroll
                    for (int r = 0; r < 4; ++r)
                        msgv[mt][tt][r] = a3[mt][tt][r] + bv[tt];
        } else {               // msg_x: dvec[row] += vec3[col]*msg_v + x_ij*msg_x
#pragma unroll
            for (int mt = 0; mt < 4; ++mt)
#pragma unroll
                for (int r = 0; r < 4; ++r) {
                    int e = mt * 16 + kg * 4 + r;
                    const size_t cb = (size_t)s_col[e] * 1152 + 256;
                    const size_t rb = (size_t)s_row[e] * 384;
                    const float xj0 = s_xij[e][0], xj1 = s_xij[e][1], xj2 = s_xij[e][2];
#pragma unroll
                    for (int tt = 0; tt < 2; ++tt) {
                        int n = nb + tt * 16 + m;
                        float mx = a3[mt][tt][r] + bv[tt];
                        float mv = msgv[mt][tt][r];
                        const float* v3 = vecp + cb + n;
                        float* dst = dvec + rb + n;
                        atomicAdd(dst,       v3[0]   * mv + xj0 * mx);
                        atomicAdd(dst + 128, v3[384] * mv + xj1 * mx);
                        atomicAdd(dst + 256, v3[768] * mv + xj2 * mx);
                    }
                }
        }
    }
}

// ---------------------------------------------------------------------------
extern "C" void kernel_launch(void* const* d_in, const int* in_sizes, int n_in,
                              void* d_out, int out_size, void* d_ws, size_t ws_size,
                              hipStream_t stream)
{
    const float* h     = (const float*)d_in[0];
    const float* vec   = (const float*)d_in[1];
    const float* coord = (const float*)d_in[2];
    const int*   eidx  = (const int*)  d_in[3];
    const float* eattr = (const float*)d_in[4];
    const float* Wvp   = (const float*)d_in[5];
    const float* W1    = (const float*)d_in[6];
    const float* b1    = (const float*)d_in[7];
    const float* W2    = (const float*)d_in[8];
    const float* b2    = (const float*)d_in[9];
    const float* W3    = (const float*)d_in[10];
    const float* b3    = (const float*)d_in[11];
    const float* Wop   = (const float*)d_in[12];
    const float* bop   = (const float*)d_in[13];

    if (ws_size < WS_FLOATS * sizeof(float)) return;  // ~333.7 MB scratch

    float* ws   = (float*)d_ws;
    float* vecp = ws + OFF_VECP;
    float* hagg = ws + OFF_HAGG;
    float* hw   = ws + OFF_HW;
    float* obuf = ws + OFF_OBUF;
    short* wt   = (short*)(ws + OFF_WT);
    float* dh   = (float*)d_out;
    float* dvec = (float*)d_out + (size_t)NN * HID;

    dim3 b256(256);
    // 0) weights -> split bf16 [n][k]
    wprep_kernel<<<864, b256, 0, stream>>>(W1, W2, W3, Wvp, Wop, wt);
    // 1) vecp = vec @ Wvp      [150000,128]x[128,384]
    gemm_node<6><<<4688, b256, 0, stream>>>(vec, 150000, wt + O_VPH, wt + O_VPL, vecp, nullptr);
    // 2) hw = h @ [W1a|W1b]    [50000,128]x[128,256]
    gemm_node<4><<<1563, b256, 0, stream>>>(h, 50000, wt + O_HWH, wt + O_HWL, hw, nullptr);
    // 3) zero h_aggr + dvec
    prep_kernel<<<25000, b256, 0, stream>>>(hagg, dvec);
    // 4) fused per-edge MLP + scatter
    edge_kernel<<<6250, b256, 0, stream>>>(vecp, hw, coord, eidx, eattr, wt,
                                           b1, b2, b3, hagg, dvec);
    // 5) obuf = h_aggr @ Wop + bop
    gemm_node<6><<<1563, b256, 0, stream>>>(hagg, 50000, wt + O_OPH, wt + O_OPL, obuf, bop);
    // 6) dh = vdot*o2 + o3 ; dvec += vec3*o1
    fin_kernel<<<25000, b256, 0, stream>>>(vecp, obuf, dh, dvec);
}

// Round 4
// 1363.422 us; speedup vs baseline: 2.5697x; 1.3299x over previous
//
#include <hip/hip_runtime.h>
#include <math.h>

// Problem constants
constexpr int NN    = 50000;
constexpr int NE    = 400000;
constexpr int HID   = 128;

// Workspace layout (float offsets). hw dead after edge_kernel; obuf overlaps it.
constexpr size_t OFF_VECP = 0;            // [N,3,384]   57.6M
constexpr size_t OFF_HAGG = 57600000;     // [N,128]      6.4M
constexpr size_t OFF_HW   = 64000000;     // [N,256]     12.8M (dead after edge)
constexpr size_t OFF_OBUF = 64000000;     // [N,384]     19.2M (after edge)
constexpr size_t OFF_WT   = 83200000;     // weights, 442368 shorts = 221184 floats
constexpr size_t OFF_PERM = 83421184;     // int[400000]
constexpr size_t OFF_DEG  = 83821184;     // int[50000]
constexpr size_t OFF_CUR  = 83871184;     // int[50000]
constexpr size_t WS_FLOATS = 83921184;    // ~335.7 MB

// split-bf16 weight offsets (shorts, within wt region)
constexpr size_t O_HWH = 0;        // [256n][128k]  h-part of W1 (rows 0..255)
constexpr size_t O_HWL = 32768;
constexpr size_t O_W1H = 65536;    // [128n][192k]  cross|rbf|eattr|pad
constexpr size_t O_W1L = 90112;
constexpr size_t O_W2H = 114688;   // [128n][128k]
constexpr size_t O_W2L = 131072;
constexpr size_t O_W3H = 147456;   // [384n][128k]
constexpr size_t O_W3L = 196608;
constexpr size_t O_VPH = 245760;   // [384n][128k]  Wvp^T
constexpr size_t O_VPL = 294912;
constexpr size_t O_OPH = 344064;   // [384n][128k]  Wop^T
constexpr size_t O_OPL = 393216;

typedef __attribute__((ext_vector_type(8))) short short8;
typedef __attribute__((ext_vector_type(4))) float f32x4;

__device__ __forceinline__ short f2bf_rne(float f) {
    unsigned u = __float_as_uint(f);
    u += 0x7fffu + ((u >> 16) & 1u);
    return (short)(u >> 16);
}
__device__ __forceinline__ float bf2f(short h) {
    return __uint_as_float(((unsigned)(unsigned short)h) << 16);
}
__device__ __forceinline__ void split8(const float* t, short8& ah, short8& al) {
#pragma unroll
    for (int j = 0; j < 8; ++j) {
        short hi = f2bf_rne(t[j]);
        ah[j] = hi;
        al[j] = f2bf_rne(t[j] - bf2f(hi));
    }
}
__device__ __forceinline__ f32x4 mfma3(short8 ah, short8 al, short8 bh, short8 bl, f32x4 c) {
    c = __builtin_amdgcn_mfma_f32_16x16x32_bf16(ah, bh, c, 0, 0, 0);
    c = __builtin_amdgcn_mfma_f32_16x16x32_bf16(al, bh, c, 0, 0, 0);
    c = __builtin_amdgcn_mfma_f32_16x16x32_bf16(ah, bl, c, 0, 0, 0);
    return c;
}

#define VLOAD8(dst, src) do { \
    *(float4*)&(dst)[0] = *(const float4*)(src); \
    *(float4*)&(dst)[4] = *(const float4*)((src) + 4); } while (0)

// ---------------------------------------------------------------------------
// Counting sort of edges by row: hist -> exclusive scan -> scatter
// ---------------------------------------------------------------------------
__global__ void sort_hist(const int* __restrict__ eidx, int* __restrict__ deg)
{
    int e = blockIdx.x * 256 + threadIdx.x;
    if (e < NE) atomicAdd(&deg[eidx[e]], 1);
}

__global__ void __launch_bounds__(1024)
sort_scan(const int* __restrict__ deg, int* __restrict__ cursor)
{
    __shared__ int part[1024];
    const int tid = threadIdx.x;
    const int base = tid * 49;                 // 1024*49 = 50176 >= 50000
    int s = 0;
#pragma unroll 7
    for (int j = 0; j < 49; ++j) {
        int i = base + j;
        if (i < NN) s += deg[i];
    }
    part[tid] = s;
    __syncthreads();
    for (int off = 1; off < 1024; off <<= 1) {
        int v = (tid >= off) ? part[tid - off] : 0;
        __syncthreads();
        part[tid] += v;
        __syncthreads();
    }
    int run = part[tid] - s;                   // exclusive prefix of this chunk
    for (int j = 0; j < 49; ++j) {
        int i = base + j;
        if (i < NN) { cursor[i] = run; run += deg[i]; }
    }
}

__global__ void sort_scatter(const int* __restrict__ eidx, int* __restrict__ cursor,
                             int* __restrict__ perm)
{
    int e = blockIdx.x * 256 + threadIdx.x;
    if (e < NE) {
        int pos = atomicAdd(&cursor[eidx[e]], 1);
        perm[pos] = e;
    }
}

// ---------------------------------------------------------------------------
// Weight prep: all weights -> split bf16 hi/lo, transposed to [n][k].
// ---------------------------------------------------------------------------
__global__ void wprep_kernel(const float* __restrict__ W1, const float* __restrict__ W2,
                             const float* __restrict__ W3, const float* __restrict__ Wvp,
                             const float* __restrict__ Wop, short* __restrict__ wt)
{
    int idx = blockIdx.x * 256 + threadIdx.x;
    float v; size_t oh, ol;
    if (idx < 32768) {                        // hw: [256][128], W1 rows 0..255
        int j = idx >> 7, k = idx & 127;
        v = (j < 128) ? W1[(size_t)k * 128 + j] : W1[(size_t)(128 + k) * 128 + (j - 128)];
        oh = O_HWH + idx; ol = O_HWL + idx;
    } else if (idx < 57344) {                 // W1cde: [128][192]
        int l = idx - 32768; int n = l / 192, k = l - n * 192;
        int r = (k < 128) ? (288 + k) : (k < 160) ? (256 + k - 128) : (k < 176) ? (416 + k - 160) : -1;
        v = (r < 0) ? 0.f : W1[(size_t)r * 128 + n];
        oh = O_W1H + l; ol = O_W1L + l;
    } else if (idx < 73728) {                 // W2t [128][128]
        int l = idx - 57344; int n = l >> 7, k = l & 127;
        v = W2[(size_t)k * 128 + n];
        oh = O_W2H + l; ol = O_W2L + l;
    } else if (idx < 122880) {                // W3t [384][128]
        int l = idx - 73728; int n = l >> 7, k = l & 127;
        v = W3[(size_t)k * 384 + n];
        oh = O_W3H + l; ol = O_W3L + l;
    } else if (idx < 172032) {                // Wvpt [384][128]
        int l = idx - 122880; int n = l >> 7, k = l & 127;
        v = Wvp[(size_t)k * 384 + n];
        oh = O_VPH + l; ol = O_VPL + l;
    } else {                                  // Wopt [384][128]
        int l = idx - 172032; int n = l >> 7, k = l & 127;
        v = Wop[(size_t)k * 384 + n];
        oh = O_OPH + l; ol = O_OPL + l;
    }
    short hi = f2bf_rne(v);
    wt[oh] = hi;
    wt[ol] = f2bf_rne(v - bf2f(hi));
}

// ---------------------------------------------------------------------------
// Node GEMM: C[M, NT*64] = A[M,128] @ Wt^T (+bias), split-bf16 MFMA.
// ---------------------------------------------------------------------------
template<int NT>
__global__ void __launch_bounds__(256, 3)
gemm_node(const float* __restrict__ A, int M,
          const short* __restrict__ wh, const short* __restrict__ wl,
          float* __restrict__ C, const float* __restrict__ bias)
{
    const int N = NT * 64;
    const int tid = threadIdx.x, wave = tid >> 6, lane = tid & 63;
    const int m = lane & 15, kg = lane >> 4;
    const int gm0 = blockIdx.x * 32;
    const int nb = wave * NT * 16;
    const f32x4 zf = {0.f, 0.f, 0.f, 0.f};
    f32x4 acc[2][NT];
#pragma unroll
    for (int mt = 0; mt < 2; ++mt)
#pragma unroll
        for (int tt = 0; tt < NT; ++tt) acc[mt][tt] = zf;

    for (int ks = 0; ks < 4; ++ks) {
        short8 ah[2], al[2];
#pragma unroll
        for (int mt = 0; mt < 2; ++mt) {
            int r = gm0 + mt * 16 + m;
            if (r >= M) r = M - 1;
            float tmp[8];
            VLOAD8(tmp, A + (size_t)r * 128 + ks * 32 + kg * 8);
            split8(tmp, ah[mt], al[mt]);
        }
#pragma unroll
        for (int tt = 0; tt < NT; ++tt) {
            size_t wo = (size_t)(nb + tt * 16 + m) * 128 + ks * 32 + kg * 8;
            short8 bh = *(const short8*)(wh + wo);
            short8 bl = *(const short8*)(wl + wo);
#pragma unroll
            for (int mt = 0; mt < 2; ++mt)
                acc[mt][tt] = mfma3(ah[mt], al[mt], bh, bl, acc[mt][tt]);
        }
    }
    float bv[NT];
#pragma unroll
    for (int tt = 0; tt < NT; ++tt) bv[tt] = bias ? bias[nb + tt * 16 + m] : 0.f;
#pragma unroll
    for (int mt = 0; mt < 2; ++mt)
#pragma unroll
        for (int r = 0; r < 4; ++r) {
            int row = gm0 + mt * 16 + kg * 4 + r;
            if (row < M) {
#pragma unroll
                for (int tt = 0; tt < NT; ++tt)
                    C[(size_t)row * N + nb + tt * 16 + m] = acc[mt][tt][r] + bv[tt];
            }
        }
}

// ---------------------------------------------------------------------------
// prep: zero h_aggr and the dvec region of d_out
// ---------------------------------------------------------------------------
__global__ void prep_kernel(float* __restrict__ hagg, float* __restrict__ dvec)
{
    int idx = blockIdx.x * 256 + threadIdx.x;
    int n = idx >> 7, k = idx & 127;
    hagg[idx] = 0.f;
    size_t db = (size_t)n * 384 + k;
    dvec[db] = 0.f; dvec[db + 128] = 0.f; dvec[db + 256] = 0.f;
}

// ---------------------------------------------------------------------------
// finalize: vdot inline; dh = vdot*o2 + o3; dvec += vec3*o1
// ---------------------------------------------------------------------------
__global__ void fin_kernel(const float* __restrict__ vecp, const float* __restrict__ obuf,
                           float* __restrict__ dh, float* __restrict__ dvec)
{
    int idx = blockIdx.x * 256 + threadIdx.x;
    int n = idx >> 7, k = idx & 127;
    size_t b = (size_t)n * 1152;
    float vd = vecp[b + k]       * vecp[b + 128 + k]
             + vecp[b + 384 + k] * vecp[b + 512 + k]
             + vecp[b + 768 + k] * vecp[b + 896 + k];
    const float* o = obuf + (size_t)n * 384;
    float o1 = o[k], o2 = o[128 + k], o3 = o[256 + k];
    dh[idx] = vd * o2 + o3;
    size_t vb = b + 256 + k;
    size_t db = (size_t)n * 384 + k;
    dvec[db]       += vecp[vb]       * o1;
    dvec[db + 128] += vecp[vb + 384] * o1;
    dvec[db + 256] += vecp[vb + 768] * o1;
}

// ---------------------------------------------------------------------------
// Fused edge kernel over SORTED edges. 64 edges/block, 4 waves; wave owns 32
// N-cols, loops 4 M-tiles. GEMM1 pipelined: chunk k+1 global loads issued into
// registers before MFMAs of chunk k; split+LDS-write after (waitcnt covered).
// Single-buffered A chunk -> LDS 46.8KB -> 3 blocks/CU. Atomics run-combined
// per lane over consecutive sorted edges (~2.8x fewer flushes).
// ---------------------------------------------------------------------------
__global__ void __launch_bounds__(256, 3)
edge_kernel(const float* __restrict__ vecp, const float* __restrict__ hw,
            const float* __restrict__ coord, const int* __restrict__ eidx,
            const float* __restrict__ eattr, const short* __restrict__ wt,
            const int* __restrict__ perm,
            const float* __restrict__ b1, const float* __restrict__ b2,
            const float* __restrict__ b3,
            float* __restrict__ hagg, float* __restrict__ dvec)
{
    __shared__ __align__(16) short abh[64][40];     // A chunk hi, [edge][k]
    __shared__ __align__(16) short abl[64][40];     // A chunk lo
    __shared__ __align__(16) short xh[64][136];     // x1/x2 hi, [edge][k]
    __shared__ __align__(16) short xl[64][136];
    __shared__ int   s_row[64], s_col[64], s_es[64];
    __shared__ float s_xij[64][3];
    __shared__ float s_d[64];

    const int tid = threadIdx.x;
    const int wave = tid >> 6, lane = tid & 63;
    const int m = lane & 15, kg = lane >> 4;
    const int nb = wave * 32;          // this wave's N-base
    const int eb = blockIdx.x * 64;    // E = 6250*64 exactly
    const int be = tid >> 2;           // build: edge 0..63
    const int bq = (tid & 3) * 8;      // build: k-offset {0,8,16,24}

    if (tid < 64) {
        int es = perm[eb + tid];
        int r = eidx[es], c = eidx[NE + es];
        s_es[tid] = es; s_row[tid] = r; s_col[tid] = c;
        float x0 = coord[r * 3 + 0] - coord[c * 3 + 0];
        float x1 = coord[r * 3 + 1] - coord[c * 3 + 1];
        float x2 = coord[r * 3 + 2] - coord[c * 3 + 2];
        s_xij[tid][0] = x0; s_xij[tid][1] = x1; s_xij[tid][2] = x2;
        s_d[tid] = sqrtf(x0 * x0 + x1 * x1 + x2 * x2 + 1e-8f);
    }
    __syncthreads();

    const f32x4 zf = {0.f, 0.f, 0.f, 0.f};
    const float delta = 5.0f / 31.0f;
    const float coeff = -0.5f / (delta * delta);
    const int brow = s_row[be], bcol = s_col[be], bes = s_es[be];

    // pipelined A-chunk staging: issue() = global loads only; commit() = wait+
    // compute+split+LDS write. pA..pF live across the MFMA phase.
    float pA[8], pB[8], pC[8], pD[8], pE[8], pF[8];
    auto issue = [&](int ks) {
        if (ks < 4) {                      // cross
            int kk = ks * 32 + bq;
            const float* vr = vecp + (size_t)brow * 1152 + kk;
            const float* vc = vecp + (size_t)bcol * 1152 + 128 + kk;
            VLOAD8(pA, vr);       VLOAD8(pB, vc);
            VLOAD8(pC, vr + 384); VLOAD8(pD, vc + 384);
            VLOAD8(pE, vr + 768); VLOAD8(pF, vc + 768);
        } else if (ks == 5) {
            if (bq < 16) VLOAD8(pA, eattr + (size_t)bes * 16 + bq);
        }
    };
    auto commit = [&](int ks) {
        float tmp[8];
        if (ks < 4) {
#pragma unroll
            for (int j = 0; j < 8; ++j)
                tmp[j] = pA[j] * pB[j] + pC[j] * pD[j] + pE[j] * pF[j];
        } else if (ks == 4) {              // rbf
            float dd = s_d[be];
#pragma unroll
            for (int j = 0; j < 8; ++j) {
                float x = dd - (float)(bq + j) * delta;
                tmp[j] = __expf(coeff * x * x);
            }
        } else {                           // eattr(16) + pad(16)
#pragma unroll
            for (int j = 0; j < 8; ++j) tmp[j] = (bq < 16) ? pA[j] : 0.f;
        }
        short8 sh, sl; split8(tmp, sh, sl);
        *(short8*)&abh[be][bq] = sh;
        *(short8*)&abl[be][bq] = sl;
    };

    // ---------------- GEMM1: [64e x 192] @ W1cde ----------------
    f32x4 acc[4][2];
#pragma unroll
    for (int mt = 0; mt < 4; ++mt) { acc[mt][0] = zf; acc[mt][1] = zf; }

    issue(0); commit(0);
    __syncthreads();
    for (int ks = 0; ks < 6; ++ks) {
        if (ks < 5) issue(ks + 1);         // loads in flight across MFMA phase
        short8 ah4[4], al4[4];
#pragma unroll
        for (int mt = 0; mt < 4; ++mt) {
            ah4[mt] = *(const short8*)&abh[mt * 16 + m][kg * 8];
            al4[mt] = *(const short8*)&abl[mt * 16 + m][kg * 8];
        }
#pragma unroll
        for (int tt = 0; tt < 2; ++tt) {
            size_t wo = (size_t)(nb + tt * 16 + m) * 192 + ks * 32 + kg * 8;
            short8 bh = *(const short8*)(wt + O_W1H + wo);
            short8 bl = *(const short8*)(wt + O_W1L + wo);
#pragma unroll
            for (int mt = 0; mt < 4; ++mt)
                acc[mt][tt] = mfma3(ah4[mt], al4[mt], bh, bl, acc[mt][tt]);
        }
        __syncthreads();                   // all waves done reading chunk ks
        if (ks < 5) { commit(ks + 1); __syncthreads(); }
    }

    // epilogue1: += hw[row] + hw[col] + b1, silu, split -> xh/xl
    {
        float b1v[2] = { b1[nb + m], b1[nb + 16 + m] };
#pragma unroll
        for (int mt = 0; mt < 4; ++mt)
#pragma unroll
            for (int r = 0; r < 4; ++r) {
                int e = mt * 16 + kg * 4 + r;
                const float* hr = hw + (size_t)s_row[e] * 256;
                const float* hc = hw + (size_t)s_col[e] * 256 + 128;
#pragma unroll
                for (int tt = 0; tt < 2; ++tt) {
                    int n = nb + tt * 16 + m;
                    float v = acc[mt][tt][r] + hr[n] + hc[n] + b1v[tt];
                    float sv = v * __builtin_amdgcn_rcpf(1.f + __expf(-v));
                    short hi = f2bf_rne(sv);
                    xh[e][n] = hi;
                    xl[e][n] = f2bf_rne(sv - bf2f(hi));
                }
            }
    }
    __syncthreads();

    // ---------------- GEMM2: x1 @ W2t -> x2 ----------------
#pragma unroll
    for (int mt = 0; mt < 4; ++mt) { acc[mt][0] = zf; acc[mt][1] = zf; }
    for (int ks = 0; ks < 4; ++ks) {
        short8 ah4[4], al4[4];
#pragma unroll
        for (int mt = 0; mt < 4; ++mt) {
            ah4[mt] = *(const short8*)&xh[mt * 16 + m][ks * 32 + kg * 8];
            al4[mt] = *(const short8*)&xl[mt * 16 + m][ks * 32 + kg * 8];
        }
#pragma unroll
        for (int tt = 0; tt < 2; ++tt) {
            size_t wo = (size_t)(nb + tt * 16 + m) * 128 + ks * 32 + kg * 8;
            short8 bh = *(const short8*)(wt + O_W2H + wo);
            short8 bl = *(const short8*)(wt + O_W2L + wo);
#pragma unroll
            for (int mt = 0; mt < 4; ++mt)
                acc[mt][tt] = mfma3(ah4[mt], al4[mt], bh, bl, acc[mt][tt]);
        }
    }
    {
        float b2v[2] = { b2[nb + m], b2[nb + 16 + m] };
#pragma unroll
        for (int mt = 0; mt < 4; ++mt)
#pragma unroll
            for (int tt = 0; tt < 2; ++tt)
#pragma unroll
                for (int r = 0; r < 4; ++r) {
                    float v = acc[mt][tt][r] + b2v[tt];
                    acc[mt][tt][r] = v * __builtin_amdgcn_rcpf(1.f + __expf(-v));
                }
    }
    __syncthreads();   // all waves done reading x1
#pragma unroll
    for (int mt = 0; mt < 4; ++mt)
#pragma unroll
        for (int tt = 0; tt < 2; ++tt)
#pragma unroll
            for (int r = 0; r < 4; ++r) {
                int e = mt * 16 + kg * 4 + r;
                int n = nb + tt * 16 + m;
                float sv = acc[mt][tt][r];
                short hi = f2bf_rne(sv);
                xh[e][n] = hi;
                xl[e][n] = f2bf_rne(sv - bf2f(hi));
            }
    __syncthreads();

    // ---------------- GEMM3: x2 @ W3t (3 col-tiles) + combined scatter ----
    float msgv[4][2][4];
    for (int c = 0; c < 3; ++c) {
        f32x4 a3[4][2];
#pragma unroll
        for (int mt = 0; mt < 4; ++mt) { a3[mt][0] = zf; a3[mt][1] = zf; }
        for (int ks = 0; ks < 4; ++ks) {
            short8 ah4[4], al4[4];
#pragma unroll
            for (int mt = 0; mt < 4; ++mt) {
                ah4[mt] = *(const short8*)&xh[mt * 16 + m][ks * 32 + kg * 8];
                al4[mt] = *(const short8*)&xl[mt * 16 + m][ks * 32 + kg * 8];
            }
#pragma unroll
            for (int tt = 0; tt < 2; ++tt) {
                size_t wo = (size_t)(c * 128 + nb + tt * 16 + m) * 128 + ks * 32 + kg * 8;
                short8 bh = *(const short8*)(wt + O_W3H + wo);
                short8 bl = *(const short8*)(wt + O_W3L + wo);
#pragma unroll
                for (int mt = 0; mt < 4; ++mt)
                    a3[mt][tt] = mfma3(ah4[mt], al4[mt], bh, bl, a3[mt][tt]);
            }
        }
        float bv[2] = { b3[c * 128 + nb + m], b3[c * 128 + nb + 16 + m] };
        const int n0 = nb + m, n1 = nb + 16 + m;
        if (c == 0) {          // msg_h -> h_aggr[row], run-combined
            int cur = s_row[kg * 4];
            float s0 = 0.f, s1 = 0.f;
#pragma unroll
            for (int mt = 0; mt < 4; ++mt)
#pragma unroll
                for (int r = 0; r < 4; ++r) {
                    int rr = s_row[mt * 16 + kg * 4 + r];
                    float v0 = a3[mt][0][r] + bv[0];
                    float v1 = a3[mt][1][r] + bv[1];
                    if (rr != cur) {
                        atomicAdd(&hagg[(size_t)cur * 128 + n0], s0);
                        atomicAdd(&hagg[(size_t)cur * 128 + n1], s1);
                        cur = rr; s0 = 0.f; s1 = 0.f;
                    }
                    s0 += v0; s1 += v1;
                }
            atomicAdd(&hagg[(size_t)cur * 128 + n0], s0);
            atomicAdd(&hagg[(size_t)cur * 128 + n1], s1);
        } else if (c == 1) {   // msg_v: keep in registers
#pragma unroll
            for (int mt = 0; mt < 4; ++mt)
#pragma unroll
                for (int tt = 0; tt < 2; ++tt)
#pragma unroll
                    for (int r = 0; r < 4; ++r)
                        msgv[mt][tt][r] = a3[mt][tt][r] + bv[tt];
        } else {               // msg_x: dvec[row] += vec3[col]*msg_v + x_ij*msg_x
            int cur = s_row[kg * 4];
            float sd[6] = {0.f, 0.f, 0.f, 0.f, 0.f, 0.f};
#pragma unroll
            for (int mt = 0; mt < 4; ++mt)
#pragma unroll
                for (int r = 0; r < 4; ++r) {
                    int e = mt * 16 + kg * 4 + r;
                    int rr = s_row[e];
                    if (rr != cur) {
                        float* dst = dvec + (size_t)cur * 384;
                        atomicAdd(dst + n0,       sd[0]);
                        atomicAdd(dst + 128 + n0, sd[1]);
                        atomicAdd(dst + 256 + n0, sd[2]);
                        atomicAdd(dst + n1,       sd[3]);
                        atomicAdd(dst + 128 + n1, sd[4]);
                        atomicAdd(dst + 256 + n1, sd[5]);
                        cur = rr;
#pragma unroll
                        for (int q = 0; q < 6; ++q) sd[q] = 0.f;
                    }
                    const float* v3 = vecp + (size_t)s_col[e] * 1152 + 256;
                    const float xj0 = s_xij[e][0], xj1 = s_xij[e][1], xj2 = s_xij[e][2];
                    float mx0 = a3[mt][0][r] + bv[0], mx1 = a3[mt][1][r] + bv[1];
                    float mv0 = msgv[mt][0][r],       mv1 = msgv[mt][1][r];
                    sd[0] += v3[n0]       * mv0 + xj0 * mx0;
                    sd[1] += v3[384 + n0] * mv0 + xj1 * mx0;
                    sd[2] += v3[768 + n0] * mv0 + xj2 * mx0;
                    sd[3] += v3[n1]       * mv1 + xj0 * mx1;
                    sd[4] += v3[384 + n1] * mv1 + xj1 * mx1;
                    sd[5] += v3[768 + n1] * mv1 + xj2 * mx1;
                }
            float* dst = dvec + (size_t)cur * 384;
            atomicAdd(dst + n0,       sd[0]);
            atomicAdd(dst + 128 + n0, sd[1]);
            atomicAdd(dst + 256 + n0, sd[2]);
            atomicAdd(dst + n1,       sd[3]);
            atomicAdd(dst + 128 + n1, sd[4]);
            atomicAdd(dst + 256 + n1, sd[5]);
        }
    }
}

// ---------------------------------------------------------------------------
extern "C" void kernel_launch(void* const* d_in, const int* in_sizes, int n_in,
                              void* d_out, int out_size, void* d_ws, size_t ws_size,
                              hipStream_t stream)
{
    const float* h     = (const float*)d_in[0];
    const float* vec   = (const float*)d_in[1];
    const float* coord = (const float*)d_in[2];
    const int*   eidx  = (const int*)  d_in[3];
    const float* eattr = (const float*)d_in[4];
    const float* Wvp   = (const float*)d_in[5];
    const float* W1    = (const float*)d_in[6];
    const float* b1    = (const float*)d_in[7];
    const float* W2    = (const float*)d_in[8];
    const float* b2    = (const float*)d_in[9];
    const float* W3    = (const float*)d_in[10];
    const float* b3    = (const float*)d_in[11];
    const float* Wop   = (const float*)d_in[12];
    const float* bop   = (const float*)d_in[13];

    if (ws_size < WS_FLOATS * sizeof(float)) return;  // ~335.7 MB scratch

    float* ws   = (float*)d_ws;
    float* vecp = ws + OFF_VECP;
    float* hagg = ws + OFF_HAGG;
    float* hw   = ws + OFF_HW;
    float* obuf = ws + OFF_OBUF;
    short* wt   = (short*)(ws + OFF_WT);
    int*   perm = (int*)(ws + OFF_PERM);
    int*   deg  = (int*)(ws + OFF_DEG);
    int*   cur  = (int*)(ws + OFF_CUR);
    float* dh   = (float*)d_out;
    float* dvec = (float*)d_out + (size_t)NN * HID;

    dim3 b256(256);
    // sort edges by row (counting sort)
    hipMemsetAsync(deg, 0, NN * sizeof(int), stream);
    sort_hist<<<1563, b256, 0, stream>>>(eidx, deg);
    sort_scan<<<1, 1024, 0, stream>>>(deg, cur);
    sort_scatter<<<1563, b256, 0, stream>>>(eidx, cur, perm);
    // weights -> split bf16 [n][k]
    wprep_kernel<<<864, b256, 0, stream>>>(W1, W2, W3, Wvp, Wop, wt);
    // vecp = vec @ Wvp      [150000,128]x[128,384]
    gemm_node<6><<<4688, b256, 0, stream>>>(vec, 150000, wt + O_VPH, wt + O_VPL, vecp, nullptr);
    // hw = h @ [W1a|W1b]    [50000,128]x[128,256]
    gemm_node<4><<<1563, b256, 0, stream>>>(h, 50000, wt + O_HWH, wt + O_HWL, hw, nullptr);
    // zero h_aggr + dvec
    prep_kernel<<<25000, b256, 0, stream>>>(hagg, dvec);
    // fused per-edge MLP + combined scatter (sorted order)
    edge_kernel<<<6250, b256, 0, stream>>>(vecp, hw, coord, eidx, eattr, wt, perm,
                                           b1, b2, b3, hagg, dvec);
    // obuf = h_aggr @ Wop + bop
    gemm_node<6><<<1563, b256, 0, stream>>>(hagg, 50000, wt + O_OPH, wt + O_OPL, obuf, bop);
    // dh = vdot*o2 + o3 ; dvec += vec3*o1
    fin_kernel<<<25000, b256, 0, stream>>>(vecp, obuf, dh, dvec);
}

// Round 5
// 1313.202 us; speedup vs baseline: 2.6680x; 1.0382x over previous
//
#include <hip/hip_runtime.h>
#include <math.h>

// Problem constants
constexpr int NN    = 50000;
constexpr int NE    = 400000;
constexpr int HID   = 128;

// Workspace layout (float offsets)
constexpr size_t OFF_VECP = 0;            // [N,3,384]   57.6M
constexpr size_t OFF_HAGG = 57600000;     // [N,128]      6.4M
constexpr size_t OFF_HW   = 64000000;     // [N,256]     12.8M
constexpr size_t OFF_WT   = 83200000;     // weights, 442368 shorts
constexpr size_t OFF_PERM = 83421184;     // int[400000]
constexpr size_t OFF_DEG  = 83821184;     // int[50000]
constexpr size_t OFF_CUR  = 83871184;     // int[50000]
constexpr size_t WS_FLOATS = 83921184;    // ~335.7 MB

// split-bf16 weight offsets (shorts, within wt region)
constexpr size_t O_HWH = 0;        // [256n][128k]
constexpr size_t O_HWL = 32768;
constexpr size_t O_W1H = 65536;    // [128n][192k]
constexpr size_t O_W1L = 90112;
constexpr size_t O_W2H = 114688;   // [128n][128k]
constexpr size_t O_W2L = 131072;
constexpr size_t O_W3H = 147456;   // [384n][128k]
constexpr size_t O_W3L = 196608;
constexpr size_t O_VPH = 245760;   // [384n][128k]
constexpr size_t O_VPL = 294912;
constexpr size_t O_OPH = 344064;   // [384n][128k]
constexpr size_t O_OPL = 393216;

typedef __attribute__((ext_vector_type(8))) short short8;
typedef __attribute__((ext_vector_type(4))) float f32x4;

__device__ __forceinline__ short f2bf_rne(float f) {
    unsigned u = __float_as_uint(f);
    u += 0x7fffu + ((u >> 16) & 1u);
    return (short)(u >> 16);
}
__device__ __forceinline__ float bf2f(short h) {
    return __uint_as_float(((unsigned)(unsigned short)h) << 16);
}
__device__ __forceinline__ void split8(const float* t, short8& ah, short8& al) {
#pragma unroll
    for (int j = 0; j < 8; ++j) {
        short hi = f2bf_rne(t[j]);
        ah[j] = hi;
        al[j] = f2bf_rne(t[j] - bf2f(hi));
    }
}
__device__ __forceinline__ f32x4 mfma3(short8 ah, short8 al, short8 bh, short8 bl, f32x4 c) {
    c = __builtin_amdgcn_mfma_f32_16x16x32_bf16(ah, bh, c, 0, 0, 0);
    c = __builtin_amdgcn_mfma_f32_16x16x32_bf16(al, bh, c, 0, 0, 0);
    c = __builtin_amdgcn_mfma_f32_16x16x32_bf16(ah, bl, c, 0, 0, 0);
    return c;
}

#define VLOAD8(dst, src) do { \
    *(float4*)&(dst)[0] = *(const float4*)(src); \
    *(float4*)&(dst)[4] = *(const float4*)((src) + 4); } while (0)

// ---------------------------------------------------------------------------
// misc: zero hagg/dvec (grid 25000) + wprep (blocks <864) + sort hist (<1563)
// ---------------------------------------------------------------------------
__global__ void misc_kernel(const float* __restrict__ W1, const float* __restrict__ W2,
                            const float* __restrict__ W3, const float* __restrict__ Wvp,
                            const float* __restrict__ Wop, short* __restrict__ wt,
                            const int* __restrict__ eidx, int* __restrict__ deg,
                            float* __restrict__ hagg, float* __restrict__ dvec)
{
    const int bid = blockIdx.x;
    const int idx = bid * 256 + threadIdx.x;
    // zero hagg + dvec region (exactly N*128 threads)
    {
        int n = idx >> 7, k = idx & 127;
        hagg[idx] = 0.f;
        size_t db = (size_t)n * 384 + k;
        dvec[db] = 0.f; dvec[db + 128] = 0.f; dvec[db + 256] = 0.f;
    }
    if (bid < 864) {   // weight split/transpose, idx < 221184
        float v; size_t oh, ol;
        if (idx < 32768) {
            int j = idx >> 7, k = idx & 127;
            v = (j < 128) ? W1[(size_t)k * 128 + j] : W1[(size_t)(128 + k) * 128 + (j - 128)];
            oh = O_HWH + idx; ol = O_HWL + idx;
        } else if (idx < 57344) {
            int l = idx - 32768; int n = l / 192, k = l - n * 192;
            int r = (k < 128) ? (288 + k) : (k < 160) ? (256 + k - 128) : (k < 176) ? (416 + k - 160) : -1;
            v = (r < 0) ? 0.f : W1[(size_t)r * 128 + n];
            oh = O_W1H + l; ol = O_W1L + l;
        } else if (idx < 73728) {
            int l = idx - 57344; int n = l >> 7, k = l & 127;
            v = W2[(size_t)k * 128 + n];
            oh = O_W2H + l; ol = O_W2L + l;
        } else if (idx < 122880) {
            int l = idx - 73728; int n = l >> 7, k = l & 127;
            v = W3[(size_t)k * 384 + n];
            oh = O_W3H + l; ol = O_W3L + l;
        } else if (idx < 172032) {
            int l = idx - 122880; int n = l >> 7, k = l & 127;
            v = Wvp[(size_t)k * 384 + n];
            oh = O_VPH + l; ol = O_VPL + l;
        } else {
            int l = idx - 172032; int n = l >> 7, k = l & 127;
            v = Wop[(size_t)k * 384 + n];
            oh = O_OPH + l; ol = O_OPL + l;
        }
        short hi = f2bf_rne(v);
        wt[oh] = hi;
        wt[ol] = f2bf_rne(v - bf2f(hi));
    }
    if (bid < 1563 && idx < NE)   // degree histogram
        atomicAdd(&deg[eidx[idx]], 1);
}

__global__ void __launch_bounds__(1024)
sort_scan(const int* __restrict__ deg, int* __restrict__ cursor)
{
    __shared__ int part[1024];
    const int tid = threadIdx.x;
    const int base = tid * 49;
    int s = 0;
#pragma unroll 7
    for (int j = 0; j < 49; ++j) {
        int i = base + j;
        if (i < NN) s += deg[i];
    }
    part[tid] = s;
    __syncthreads();
    for (int off = 1; off < 1024; off <<= 1) {
        int v = (tid >= off) ? part[tid - off] : 0;
        __syncthreads();
        part[tid] += v;
        __syncthreads();
    }
    int run = part[tid] - s;
    for (int j = 0; j < 49; ++j) {
        int i = base + j;
        if (i < NN) { cursor[i] = run; run += deg[i]; }
    }
}

__global__ void sort_scatter(const int* __restrict__ eidx, int* __restrict__ cursor,
                             int* __restrict__ perm)
{
    int e = blockIdx.x * 256 + threadIdx.x;
    if (e < NE) {
        int pos = atomicAdd(&cursor[eidx[e]], 1);
        perm[pos] = e;
    }
}

// ---------------------------------------------------------------------------
// Node GEMM: C[M, NT*64] = A[M,128] @ Wt^T (+bias), split-bf16 MFMA.
// ---------------------------------------------------------------------------
template<int NT>
__global__ void __launch_bounds__(256, 3)
gemm_node(const float* __restrict__ A, int M,
          const short* __restrict__ wh, const short* __restrict__ wl,
          float* __restrict__ C, const float* __restrict__ bias)
{
    const int N = NT * 64;
    const int tid = threadIdx.x, wave = tid >> 6, lane = tid & 63;
    const int m = lane & 15, kg = lane >> 4;
    const int gm0 = blockIdx.x * 32;
    const int nb = wave * NT * 16;
    const f32x4 zf = {0.f, 0.f, 0.f, 0.f};
    f32x4 acc[2][NT];
#pragma unroll
    for (int mt = 0; mt < 2; ++mt)
#pragma unroll
        for (int tt = 0; tt < NT; ++tt) acc[mt][tt] = zf;

    for (int ks = 0; ks < 4; ++ks) {
        short8 ah[2], al[2];
#pragma unroll
        for (int mt = 0; mt < 2; ++mt) {
            int r = gm0 + mt * 16 + m;
            if (r >= M) r = M - 1;
            float tmp[8];
            VLOAD8(tmp, A + (size_t)r * 128 + ks * 32 + kg * 8);
            split8(tmp, ah[mt], al[mt]);
        }
#pragma unroll
        for (int tt = 0; tt < NT; ++tt) {
            size_t wo = (size_t)(nb + tt * 16 + m) * 128 + ks * 32 + kg * 8;
            short8 bh = *(const short8*)(wh + wo);
            short8 bl = *(const short8*)(wl + wo);
#pragma unroll
            for (int mt = 0; mt < 2; ++mt)
                acc[mt][tt] = mfma3(ah[mt], al[mt], bh, bl, acc[mt][tt]);
        }
    }
    float bv[NT];
#pragma unroll
    for (int tt = 0; tt < NT; ++tt) bv[tt] = bias ? bias[nb + tt * 16 + m] : 0.f;
#pragma unroll
    for (int mt = 0; mt < 2; ++mt)
#pragma unroll
        for (int r = 0; r < 4; ++r) {
            int row = gm0 + mt * 16 + kg * 4 + r;
            if (row < M) {
#pragma unroll
                for (int tt = 0; tt < NT; ++tt)
                    C[(size_t)row * N + nb + tt * 16 + m] = acc[mt][tt][r] + bv[tt];
            }
        }
}

// ---------------------------------------------------------------------------
// Fused o-GEMM + finalize: o = hagg@Wop+bop computed in-register; then
// dh = vdot*o2+o3 and dvec += vec3*o1 directly (obuf never materialized).
// Wave owns cols nb..nb+31 of EACH 128-col segment (o1,o2,o3).
// ---------------------------------------------------------------------------
__global__ void __launch_bounds__(256, 3)
gemm_fin(const float* __restrict__ hagg, const float* __restrict__ vecp,
         const short* __restrict__ wh, const short* __restrict__ wl,
         const float* __restrict__ bop, float* __restrict__ dh,
         float* __restrict__ dvec, int M)
{
    const int tid = threadIdx.x, wave = tid >> 6, lane = tid & 63;
    const int m = lane & 15, kg = lane >> 4;
    const int gm0 = blockIdx.x * 32;
    const int nb = wave * 32;
    const f32x4 zf = {0.f, 0.f, 0.f, 0.f};
    f32x4 acc[2][6];   // [mt][seg*2+tt]
#pragma unroll
    for (int mt = 0; mt < 2; ++mt)
#pragma unroll
        for (int t = 0; t < 6; ++t) acc[mt][t] = zf;

    for (int ks = 0; ks < 4; ++ks) {
        short8 ah[2], al[2];
#pragma unroll
        for (int mt = 0; mt < 2; ++mt) {
            int r = gm0 + mt * 16 + m;
            if (r >= M) r = M - 1;
            float tmp[8];
            VLOAD8(tmp, hagg + (size_t)r * 128 + ks * 32 + kg * 8);
            split8(tmp, ah[mt], al[mt]);
        }
#pragma unroll
        for (int seg = 0; seg < 3; ++seg)
#pragma unroll
            for (int tt = 0; tt < 2; ++tt) {
                size_t wo = (size_t)(seg * 128 + nb + tt * 16 + m) * 128 + ks * 32 + kg * 8;
                short8 bh = *(const short8*)(wh + wo);
                short8 bl = *(const short8*)(wl + wo);
#pragma unroll
                for (int mt = 0; mt < 2; ++mt)
                    acc[mt][seg * 2 + tt] = mfma3(ah[mt], al[mt], bh, bl, acc[mt][seg * 2 + tt]);
            }
    }
    float bo[3][2];
#pragma unroll
    for (int seg = 0; seg < 3; ++seg)
#pragma unroll
        for (int tt = 0; tt < 2; ++tt) bo[seg][tt] = bop[seg * 128 + nb + tt * 16 + m];

#pragma unroll
    for (int mt = 0; mt < 2; ++mt)
#pragma unroll
        for (int r = 0; r < 4; ++r) {
            int row = gm0 + mt * 16 + kg * 4 + r;
            if (row >= M) continue;
            size_t b = (size_t)row * 1152;
#pragma unroll
            for (int tt = 0; tt < 2; ++tt) {
                int k = nb + tt * 16 + m;
                float o1 = acc[mt][0 * 2 + tt][r] + bo[0][tt];
                float o2 = acc[mt][1 * 2 + tt][r] + bo[1][tt];
                float o3 = acc[mt][2 * 2 + tt][r] + bo[2][tt];
                float vd = vecp[b + k]       * vecp[b + 128 + k]
                         + vecp[b + 384 + k] * vecp[b + 512 + k]
                         + vecp[b + 768 + k] * vecp[b + 896 + k];
                dh[(size_t)row * 128 + k] = vd * o2 + o3;
                size_t db = (size_t)row * 384 + k;
                dvec[db]       += vecp[b + 256 + k]  * o1;
                dvec[db + 128] += vecp[b + 640 + k]  * o1;
                dvec[db + 256] += vecp[b + 1024 + k] * o1;
            }
        }
}

// ---------------------------------------------------------------------------
// Fused edge kernel over SORTED edges. 64 edges/block, 4 waves; wave owns 32
// N-cols, loops 4 M-tiles. A-chunk LDS unioned with x1/x2 LDS (disjoint
// lifetimes) -> 35.8KB -> 4 blocks/CU. Scattered loads batched 2-pass.
// ---------------------------------------------------------------------------
__global__ void __launch_bounds__(256, 4)
edge_kernel(const float* __restrict__ vecp, const float* __restrict__ hw,
            const float* __restrict__ coord, const int* __restrict__ eidx,
            const float* __restrict__ eattr, const short* __restrict__ wt,
            const int* __restrict__ perm,
            const float* __restrict__ b1, const float* __restrict__ b2,
            const float* __restrict__ b3,
            float* __restrict__ hagg, float* __restrict__ dvec)
{
    // union: {abh[64][40], abl[64][40]} (GEMM1 staging, 10240B)
    //        {xh[64][136], xl[64][136]} (x1/x2, 34816B) — disjoint lifetimes
    __shared__ __align__(16) unsigned char smem[34816];
    short (*abh)[40]  = (short(*)[40])(&smem[0]);
    short (*abl)[40]  = (short(*)[40])(&smem[5120]);
    short (*xh)[136]  = (short(*)[136])(&smem[0]);
    short (*xl)[136]  = (short(*)[136])(&smem[17408]);
    __shared__ int   s_row[64], s_col[64], s_es[64];
    __shared__ float s_xij[64][3];
    __shared__ float s_d[64];

    const int tid = threadIdx.x;
    const int wave = tid >> 6, lane = tid & 63;
    const int m = lane & 15, kg = lane >> 4;
    const int nb = wave * 32;
    const int eb = blockIdx.x * 64;
    const int be = tid >> 2;
    const int bq = (tid & 3) * 8;

    if (tid < 64) {
        int es = perm[eb + tid];
        int r = eidx[es], c = eidx[NE + es];
        s_es[tid] = es; s_row[tid] = r; s_col[tid] = c;
        float x0 = coord[r * 3 + 0] - coord[c * 3 + 0];
        float x1 = coord[r * 3 + 1] - coord[c * 3 + 1];
        float x2 = coord[r * 3 + 2] - coord[c * 3 + 2];
        s_xij[tid][0] = x0; s_xij[tid][1] = x1; s_xij[tid][2] = x2;
        s_d[tid] = sqrtf(x0 * x0 + x1 * x1 + x2 * x2 + 1e-8f);
    }
    __syncthreads();

    const f32x4 zf = {0.f, 0.f, 0.f, 0.f};
    const float delta = 5.0f / 31.0f;
    const float coeff = -0.5f / (delta * delta);
    const int brow = s_row[be], bcol = s_col[be], bes = s_es[be];

    float pA[8], pB[8], pC[8], pD[8], pE[8], pF[8];
    auto issue = [&](int ks) {
        if (ks < 4) {
            int kk = ks * 32 + bq;
            const float* vr = vecp + (size_t)brow * 1152 + kk;
            const float* vc = vecp + (size_t)bcol * 1152 + 128 + kk;
            VLOAD8(pA, vr);       VLOAD8(pB, vc);
            VLOAD8(pC, vr + 384); VLOAD8(pD, vc + 384);
            VLOAD8(pE, vr + 768); VLOAD8(pF, vc + 768);
        } else if (ks == 5) {
            if (bq < 16) VLOAD8(pA, eattr + (size_t)bes * 16 + bq);
        }
    };
    auto commit = [&](int ks) {
        float tmp[8];
        if (ks < 4) {
#pragma unroll
            for (int j = 0; j < 8; ++j)
                tmp[j] = pA[j] * pB[j] + pC[j] * pD[j] + pE[j] * pF[j];
        } else if (ks == 4) {
            float dd = s_d[be];
#pragma unroll
            for (int j = 0; j < 8; ++j) {
                float x = dd - (float)(bq + j) * delta;
                tmp[j] = __expf(coeff * x * x);
            }
        } else {
#pragma unroll
            for (int j = 0; j < 8; ++j) tmp[j] = (bq < 16) ? pA[j] : 0.f;
        }
        short8 sh, sl; split8(tmp, sh, sl);
        *(short8*)&abh[be][bq] = sh;
        *(short8*)&abl[be][bq] = sl;
    };

    // ---------------- GEMM1: [64e x 192] @ W1cde ----------------
    f32x4 acc[4][2];
#pragma unroll
    for (int mt = 0; mt < 4; ++mt) { acc[mt][0] = zf; acc[mt][1] = zf; }

    issue(0); commit(0);
    __syncthreads();
    for (int ks = 0; ks < 6; ++ks) {
        if (ks < 5) issue(ks + 1);
        short8 ah4[4], al4[4];
#pragma unroll
        for (int mt = 0; mt < 4; ++mt) {
            ah4[mt] = *(const short8*)&abh[mt * 16 + m][kg * 8];
            al4[mt] = *(const short8*)&abl[mt * 16 + m][kg * 8];
        }
#pragma unroll
        for (int tt = 0; tt < 2; ++tt) {
            size_t wo = (size_t)(nb + tt * 16 + m) * 192 + ks * 32 + kg * 8;
            short8 bh = *(const short8*)(wt + O_W1H + wo);
            short8 bl = *(const short8*)(wt + O_W1L + wo);
#pragma unroll
            for (int mt = 0; mt < 4; ++mt)
                acc[mt][tt] = mfma3(ah4[mt], al4[mt], bh, bl, acc[mt][tt]);
        }
        __syncthreads();
        if (ks < 5) { commit(ks + 1); __syncthreads(); }
    }
    // after this barrier abh/abl are dead; xh/xl (same memory) become live

    // epilogue1: += hw[row] + hw[col] + b1, silu, split -> xh/xl (2-pass loads)
    {
        float b1v[2] = { b1[nb + m], b1[nb + 16 + m] };
#pragma unroll
        for (int mt = 0; mt < 4; ++mt) {
            float hb[4][4];
#pragma unroll
            for (int r = 0; r < 4; ++r) {
                int e = mt * 16 + kg * 4 + r;
                const float* hr = hw + (size_t)s_row[e] * 256;
                const float* hc = hw + (size_t)s_col[e] * 256 + 128;
                hb[r][0] = hr[nb + m];      hb[r][1] = hc[nb + m];
                hb[r][2] = hr[nb + 16 + m]; hb[r][3] = hc[nb + 16 + m];
            }
#pragma unroll
            for (int r = 0; r < 4; ++r) {
                int e = mt * 16 + kg * 4 + r;
#pragma unroll
                for (int tt = 0; tt < 2; ++tt) {
                    int n = nb + tt * 16 + m;
                    float v = acc[mt][tt][r] + hb[r][tt * 2] + hb[r][tt * 2 + 1] + b1v[tt];
                    float sv = v * __builtin_amdgcn_rcpf(1.f + __expf(-v));
                    short hi = f2bf_rne(sv);
                    xh[e][n] = hi;
                    xl[e][n] = f2bf_rne(sv - bf2f(hi));
                }
            }
        }
    }
    __syncthreads();

    // ---------------- GEMM2: x1 @ W2t -> x2 ----------------
#pragma unroll
    for (int mt = 0; mt < 4; ++mt) { acc[mt][0] = zf; acc[mt][1] = zf; }
    for (int ks = 0; ks < 4; ++ks) {
        short8 ah4[4], al4[4];
#pragma unroll
        for (int mt = 0; mt < 4; ++mt) {
            ah4[mt] = *(const short8*)&xh[mt * 16 + m][ks * 32 + kg * 8];
            al4[mt] = *(const short8*)&xl[mt * 16 + m][ks * 32 + kg * 8];
        }
#pragma unroll
        for (int tt = 0; tt < 2; ++tt) {
            size_t wo = (size_t)(nb + tt * 16 + m) * 128 + ks * 32 + kg * 8;
            short8 bh = *(const short8*)(wt + O_W2H + wo);
            short8 bl = *(const short8*)(wt + O_W2L + wo);
#pragma unroll
            for (int mt = 0; mt < 4; ++mt)
                acc[mt][tt] = mfma3(ah4[mt], al4[mt], bh, bl, acc[mt][tt]);
        }
    }
    {
        float b2v[2] = { b2[nb + m], b2[nb + 16 + m] };
#pragma unroll
        for (int mt = 0; mt < 4; ++mt)
#pragma unroll
            for (int tt = 0; tt < 2; ++tt)
#pragma unroll
                for (int r = 0; r < 4; ++r) {
                    float v = acc[mt][tt][r] + b2v[tt];
                    acc[mt][tt][r] = v * __builtin_amdgcn_rcpf(1.f + __expf(-v));
                }
    }
    __syncthreads();
#pragma unroll
    for (int mt = 0; mt < 4; ++mt)
#pragma unroll
        for (int tt = 0; tt < 2; ++tt)
#pragma unroll
            for (int r = 0; r < 4; ++r) {
                int e = mt * 16 + kg * 4 + r;
                int n = nb + tt * 16 + m;
                float sv = acc[mt][tt][r];
                short hi = f2bf_rne(sv);
                xh[e][n] = hi;
                xl[e][n] = f2bf_rne(sv - bf2f(hi));
            }
    __syncthreads();

    // ---------------- GEMM3: x2 @ W3t (3 col-tiles) + combined scatter ----
    float msgv[4][2][4];
    for (int c = 0; c < 3; ++c) {
        f32x4 a3[4][2];
#pragma unroll
        for (int mt = 0; mt < 4; ++mt) { a3[mt][0] = zf; a3[mt][1] = zf; }
        for (int ks = 0; ks < 4; ++ks) {
            short8 ah4[4], al4[4];
#pragma unroll
            for (int mt = 0; mt < 4; ++mt) {
                ah4[mt] = *(const short8*)&xh[mt * 16 + m][ks * 32 + kg * 8];
                al4[mt] = *(const short8*)&xl[mt * 16 + m][ks * 32 + kg * 8];
            }
#pragma unroll
            for (int tt = 0; tt < 2; ++tt) {
                size_t wo = (size_t)(c * 128 + nb + tt * 16 + m) * 128 + ks * 32 + kg * 8;
                short8 bh = *(const short8*)(wt + O_W3H + wo);
                short8 bl = *(const short8*)(wt + O_W3L + wo);
#pragma unroll
                for (int mt = 0; mt < 4; ++mt)
                    a3[mt][tt] = mfma3(ah4[mt], al4[mt], bh, bl, a3[mt][tt]);
            }
        }
        float bv[2] = { b3[c * 128 + nb + m], b3[c * 128 + nb + 16 + m] };
        const int n0 = nb + m, n1 = nb + 16 + m;
        if (c == 0) {          // msg_h -> h_aggr[row], run-combined
            int cur = s_row[kg * 4];
            float s0 = 0.f, s1 = 0.f;
#pragma unroll
            for (int mt = 0; mt < 4; ++mt)
#pragma unroll
                for (int r = 0; r < 4; ++r) {
                    int rr = s_row[mt * 16 + kg * 4 + r];
                    float v0 = a3[mt][0][r] + bv[0];
                    float v1 = a3[mt][1][r] + bv[1];
                    if (rr != cur) {
                        atomicAdd(&hagg[(size_t)cur * 128 + n0], s0);
                        atomicAdd(&hagg[(size_t)cur * 128 + n1], s1);
                        cur = rr; s0 = 0.f; s1 = 0.f;
                    }
                    s0 += v0; s1 += v1;
                }
            atomicAdd(&hagg[(size_t)cur * 128 + n0], s0);
            atomicAdd(&hagg[(size_t)cur * 128 + n1], s1);
        } else if (c == 1) {
#pragma unroll
            for (int mt = 0; mt < 4; ++mt)
#pragma unroll
                for (int tt = 0; tt < 2; ++tt)
#pragma unroll
                    for (int r = 0; r < 4; ++r)
                        msgv[mt][tt][r] = a3[mt][tt][r] + bv[tt];
        } else {               // msg_x: dvec[row] += vec3[col]*msg_v + x_ij*msg_x
            int cur = s_row[kg * 4];
            float sd[6] = {0.f, 0.f, 0.f, 0.f, 0.f, 0.f};
#pragma unroll
            for (int mt = 0; mt < 4; ++mt) {
                float v3b[4][6];   // pass 1: batch the 24 scattered loads
#pragma unroll
                for (int r = 0; r < 4; ++r) {
                    int e = mt * 16 + kg * 4 + r;
                    const float* v3 = vecp + (size_t)s_col[e] * 1152 + 256;
                    v3b[r][0] = v3[n0]; v3b[r][1] = v3[384 + n0]; v3b[r][2] = v3[768 + n0];
                    v3b[r][3] = v3[n1]; v3b[r][4] = v3[384 + n1]; v3b[r][5] = v3[768 + n1];
                }
#pragma unroll
                for (int r = 0; r < 4; ++r) {
                    int e = mt * 16 + kg * 4 + r;
                    int rr = s_row[e];
                    if (rr != cur) {
                        float* dst = dvec + (size_t)cur * 384;
                        atomicAdd(dst + n0,       sd[0]);
                        atomicAdd(dst + 128 + n0, sd[1]);
                        atomicAdd(dst + 256 + n0, sd[2]);
                        atomicAdd(dst + n1,       sd[3]);
                        atomicAdd(dst + 128 + n1, sd[4]);
                        atomicAdd(dst + 256 + n1, sd[5]);
                        cur = rr;
#pragma unroll
                        for (int q = 0; q < 6; ++q) sd[q] = 0.f;
                    }
                    const float xj0 = s_xij[e][0], xj1 = s_xij[e][1], xj2 = s_xij[e][2];
                    float mx0 = a3[mt][0][r] + bv[0], mx1 = a3[mt][1][r] + bv[1];
                    float mv0 = msgv[mt][0][r],       mv1 = msgv[mt][1][r];
                    sd[0] += v3b[r][0] * mv0 + xj0 * mx0;
                    sd[1] += v3b[r][1] * mv0 + xj1 * mx0;
                    sd[2] += v3b[r][2] * mv0 + xj2 * mx0;
                    sd[3] += v3b[r][3] * mv1 + xj0 * mx1;
                    sd[4] += v3b[r][4] * mv1 + xj1 * mx1;
                    sd[5] += v3b[r][5] * mv1 + xj2 * mx1;
                }
            }
            float* dst = dvec + (size_t)cur * 384;
            atomicAdd(dst + n0,       sd[0]);
            atomicAdd(dst + 128 + n0, sd[1]);
            atomicAdd(dst + 256 + n0, sd[2]);
            atomicAdd(dst + n1,       sd[3]);
            atomicAdd(dst + 128 + n1, sd[4]);
            atomicAdd(dst + 256 + n1, sd[5]);
        }
    }
}

// ---------------------------------------------------------------------------
extern "C" void kernel_launch(void* const* d_in, const int* in_sizes, int n_in,
                              void* d_out, int out_size, void* d_ws, size_t ws_size,
                              hipStream_t stream)
{
    const float* h     = (const float*)d_in[0];
    const float* vec   = (const float*)d_in[1];
    const float* coord = (const float*)d_in[2];
    const int*   eidx  = (const int*)  d_in[3];
    const float* eattr = (const float*)d_in[4];
    const float* Wvp   = (const float*)d_in[5];
    const float* W1    = (const float*)d_in[6];
    const float* b1    = (const float*)d_in[7];
    const float* W2    = (const float*)d_in[8];
    const float* b2    = (const float*)d_in[9];
    const float* W3    = (const float*)d_in[10];
    const float* b3    = (const float*)d_in[11];
    const float* Wop   = (const float*)d_in[12];
    const float* bop   = (const float*)d_in[13];

    if (ws_size < WS_FLOATS * sizeof(float)) return;

    float* ws   = (float*)d_ws;
    float* vecp = ws + OFF_VECP;
    float* hagg = ws + OFF_HAGG;
    float* hw   = ws + OFF_HW;
    short* wt   = (short*)(ws + OFF_WT);
    int*   perm = (int*)(ws + OFF_PERM);
    int*   deg  = (int*)(ws + OFF_DEG);
    int*   cur  = (int*)(ws + OFF_CUR);
    float* dh   = (float*)d_out;
    float* dvec = (float*)d_out + (size_t)NN * HID;

    dim3 b256(256);
    hipMemsetAsync(deg, 0, NN * sizeof(int), stream);
    // zero hagg/dvec + weight split + degree histogram (one launch)
    misc_kernel<<<25000, b256, 0, stream>>>(W1, W2, W3, Wvp, Wop, wt, eidx, deg, hagg, dvec);
    sort_scan<<<1, 1024, 0, stream>>>(deg, cur);
    sort_scatter<<<1563, b256, 0, stream>>>(eidx, cur, perm);
    // vecp = vec @ Wvp      [150000,128]x[128,384]
    gemm_node<6><<<4688, b256, 0, stream>>>(vec, 150000, wt + O_VPH, wt + O_VPL, vecp, nullptr);
    // hw = h @ [W1a|W1b]    [50000,128]x[128,256]
    gemm_node<4><<<1563, b256, 0, stream>>>(h, 50000, wt + O_HWH, wt + O_HWL, hw, nullptr);
    // fused per-edge MLP + combined scatter (sorted order)
    edge_kernel<<<6250, b256, 0, stream>>>(vecp, hw, coord, eidx, eattr, wt, perm,
                                           b1, b2, b3, hagg, dvec);
    // fused o-GEMM + finalize (obuf never materialized)
    gemm_fin<<<1563, b256, 0, stream>>>(hagg, vecp, wt + O_OPH, wt + O_OPL, bop, dh, dvec, 50000);
}